// Round 10
// baseline (461.785 us; speedup 1.0000x reference)
//
#include <hip/hip_runtime.h>

typedef unsigned short ushort_t;
typedef unsigned int u32;
typedef _Float16 f16;
typedef f16 f16x8 __attribute__((ext_vector_type(8)));
typedef f16 f16x2 __attribute__((ext_vector_type(2)));
typedef ushort_t u16x8 __attribute__((ext_vector_type(8)));
typedef float f32x4 __attribute__((ext_vector_type(4)));
typedef float f32x16 __attribute__((ext_vector_type(16)));

#define C_DIM 256
#define HW 4096
#define CHW (C_DIM*HW)
#define L2E 1.4426950408889634f

// Device-global scratch. Internal pipeline f16.
__device__ __align__(16) f16 g_xbT[4 * CHW];
__device__ __align__(16) f16 g_q[4 * CHW];
__device__ __align__(16) f16 g_k[4 * CHW];
__device__ __align__(16) f16 g_v[4 * CHW];
__device__ __align__(16) f16 g_opart[16 * CHW];   // [slot=jq*4+n][c][i] normalized O^T
__device__ __align__(16) float g_ml[16 * 2 * HW]; // [slot][{m,l}][i]

__device__ __forceinline__ float bf2f(ushort_t h) {
    union { u32 u; float f; } v; v.u = ((u32)h) << 16; return v.f;
}
__device__ __forceinline__ ushort_t f2bf(float f) {
    union { float f; u32 u; } v; v.f = f;
    u32 r = v.u + 0x7FFF + ((v.u >> 16) & 1);
    return (ushort_t)(r >> 16);
}
__device__ __forceinline__ float fin0(float v) {
    return (v > -1e30f && v < 1e30f) ? v : 0.f;
}
__device__ __forceinline__ f16 sf16(float v) {
    return (f16)((v > -1e4f && v < 1e4f) ? v : 0.f);
}
__device__ __forceinline__ void gl2lds16(const f16* g, f16* l) {
    __builtin_amdgcn_global_load_lds(
        (const __attribute__((address_space(1))) u32*)g,
        (__attribute__((address_space(3))) u32*)l, 16, 0, 0);
}
// Local dtype probe: read 64 halves as bf16; f32-misread low-halves decode huge.
__device__ __forceinline__ int probe_mode(const void* p) {
    int lane = threadIdx.x & 63;
    float v = fabsf(bf2f(((const ushort_t*)p)[lane]));
    v = (v < 1e6f) ? v : 1e6f;
#pragma unroll
    for (int d = 1; d < 64; d <<= 1) v += __shfl_xor(v, d, 64);
    return (v * (1.f / 64.f) > 100.f) ? 1 : 0;
}

__global__ void k_sentinel(ushort_t* out, int n) {
    int i = blockIdx.x * 256 + threadIdx.x;
    if (i < n) out[i] = f2bf(777.f);
}

// ---------------- kernel 1: x (N,C,HW) -> g_xbT f16 (N,HW,C) ----------------
__global__ __launch_bounds__(256) void k_transpose(const void* __restrict__ xv) {
    __shared__ f16 t[64][66];
    int mode = probe_mode(xv);
    int n = blockIdx.z, c0 = blockIdx.y * 64, l0 = blockIdx.x * 64;
    int tid = threadIdx.x;
    f16* ob = g_xbT + n * CHW;
    int lq = (tid & 15) * 4;
    int cl = tid >> 4;
    if (mode == 0) {
        const ushort_t* xb = (const ushort_t*)xv + n * CHW;
#pragma unroll
        for (int p = 0; p < 4; ++p) {
            int c = cl + 16 * p;
            ushort4 v = *(const ushort4*)(xb + (c0 + c) * HW + l0 + lq);
            t[lq + 0][c] = sf16(bf2f(v.x));
            t[lq + 1][c] = sf16(bf2f(v.y));
            t[lq + 2][c] = sf16(bf2f(v.z));
            t[lq + 3][c] = sf16(bf2f(v.w));
        }
    } else {
        const float* xb = (const float*)xv + n * CHW;
#pragma unroll
        for (int p = 0; p < 4; ++p) {
            int c = cl + 16 * p;
            float4 v = *(const float4*)(xb + (c0 + c) * HW + l0 + lq);
            t[lq + 0][c] = sf16(v.x);
            t[lq + 1][c] = sf16(v.y);
            t[lq + 2][c] = sf16(v.z);
            t[lq + 3][c] = sf16(v.w);
        }
    }
    __syncthreads();
    int c2 = (tid & 31) * 2;
    int lr = tid >> 5;
#pragma unroll
    for (int p = 0; p < 8; ++p) {
        int l = lr + 8 * p;
        u32 pair = *(const u32*)&t[l][c2];
        *(u32*)(ob + (l0 + l) * C_DIM + c0 + c2) = pair;
    }
}

// ---------------- kernel 2: projections (f16 MFMA) ----------------
__global__ __launch_bounds__(256) void k_proj(
    const void* __restrict__ Wq, const void* __restrict__ bq,
    const void* __restrict__ Wk, const void* __restrict__ bk,
    const void* __restrict__ Wv, const void* __restrict__ bv)
{
    __shared__ __align__(16) f16 lds_x[128 * 64];
    __shared__ __align__(16) f16 lds_w[128 * 64];
    int l0 = blockIdx.x * 128;
    int og0 = blockIdx.y * 128;
    int n = blockIdx.z;
    int mat = og0 >> 8;       // 0=q,1=k,2=v
    int om0 = og0 & 255;
    const void* W = (mat == 0) ? Wq : (mat == 1) ? Wk : Wv;
    const void* bias = (mat == 0) ? bq : (mat == 1) ? bk : bv;
    int mode = probe_mode(W);
    int tid = threadIdx.x, w = tid >> 6, lane = tid & 63;
    int quad = lane >> 4, l16 = lane & 15;
    const f16* xb = g_xbT + n * CHW;

    f32x4 acc[2][8];
#pragma unroll
    for (int a = 0; a < 2; a++)
#pragma unroll
        for (int b = 0; b < 8; b++) acc[a][b] = f32x4{0.f, 0.f, 0.f, 0.f};

    for (int ch = 0; ch < 4; ++ch) {
        int cc0 = ch * 64;
        f16x8 xs[4], wsr[4];
#pragma unroll
        for (int ti = 0; ti < 4; ++ti) {
            int s = (w * 4 + ti) * 64 + lane;
            int row = s >> 3, gp = s & 7;
            xs[ti] = *(const f16x8*)(xb + (l0 + row) * C_DIM + cc0 + gp * 8);
            f16x8 h;
            if (mode == 0) {
                u16x8 wv = *(const u16x8*)((const ushort_t*)W + (om0 + row) * C_DIM + cc0 + gp * 8);
#pragma unroll
                for (int e = 0; e < 8; e++) h[e] = sf16(bf2f(wv[e]));
            } else {
                const float* wf = (const float*)W + (om0 + row) * C_DIM + cc0 + gp * 8;
#pragma unroll
                for (int e = 0; e < 8; e++) h[e] = sf16(wf[e]);
            }
            wsr[ti] = h;
        }
        __syncthreads();
#pragma unroll
        for (int ti = 0; ti < 4; ++ti) {
            int s = (w * 4 + ti) * 64 + lane;
            int row = s >> 3, gp = s & 7;
            int pos = gp ^ (row & 7);
            *(f16x8*)(lds_x + (row * 8 + pos) * 8) = xs[ti];
            *(f16x8*)(lds_w + (row * 8 + pos) * 8) = wsr[ti];
        }
        __syncthreads();
#pragma unroll
        for (int ks = 0; ks < 2; ++ks) {
            f16x8 af[2];
#pragma unroll
            for (int mt = 0; mt < 2; ++mt) {
                int row = w * 32 + mt * 16 + l16;
                int g = ks * 4 + quad;
                int pos = g ^ (row & 7);
                af[mt] = *(const f16x8*)(lds_x + (row * 8 + pos) * 8);
            }
#pragma unroll
            for (int nt = 0; nt < 8; ++nt) {
                int rowo = nt * 16 + l16;
                int g = ks * 4 + quad;
                int pos = g ^ (rowo & 7);
                f16x8 bfv = *(const f16x8*)(lds_w + (rowo * 8 + pos) * 8);
                if (mat < 2) {
                    acc[0][nt] = __builtin_amdgcn_mfma_f32_16x16x32_f16(af[0], bfv, acc[0][nt], 0, 0, 0);
                    acc[1][nt] = __builtin_amdgcn_mfma_f32_16x16x32_f16(af[1], bfv, acc[1][nt], 0, 0, 0);
                } else {
                    acc[0][nt] = __builtin_amdgcn_mfma_f32_16x16x32_f16(bfv, af[0], acc[0][nt], 0, 0, 0);
                    acc[1][nt] = __builtin_amdgcn_mfma_f32_16x16x32_f16(bfv, af[1], acc[1][nt], 0, 0, 0);
                }
            }
        }
        __syncthreads();
    }

    auto loadb = [&](int i) -> float {
        return mode ? ((const float*)bias)[i] : bf2f(((const ushort_t*)bias)[i]);
    };
    if (mat < 2) {
        f16* T = ((mat == 0) ? g_q : g_k) + n * CHW;
        float bvv[8];
#pragma unroll
        for (int nt = 0; nt < 8; nt++) bvv[nt] = loadb(om0 + nt * 16 + l16);
#pragma unroll
        for (int mt = 0; mt < 2; mt++)
#pragma unroll
            for (int nt = 0; nt < 8; nt++)
#pragma unroll
                for (int r = 0; r < 4; r++) {
                    int l = l0 + w * 32 + mt * 16 + quad * 4 + r;
                    int o = om0 + nt * 16 + l16;
                    T[l * C_DIM + o] = sf16(acc[mt][nt][r] + bvv[nt]);
                }
    } else {
        f16* T = g_v + n * CHW;
#pragma unroll
        for (int mt = 0; mt < 2; mt++)
#pragma unroll
            for (int nt = 0; nt < 8; nt++)
#pragma unroll
                for (int r = 0; r < 4; r++) {
                    int o = om0 + nt * 16 + quad * 4 + r;
                    int l = l0 + w * 32 + mt * 16 + l16;
                    T[o * HW + l] = sf16(acc[mt][nt][r] + loadb(o));
                }
    }
}

// ---------------- kernel 3: flash attention (Round-7 split-drain base) ------
// ABLATION BUILD. MODE 0 = real (runs LAST, overwrites all partials).
// MODE 1 = no softmax/pack (st kept live via asm; pf=0 constants).
// MODE 3 = no PV phase (V ds_reads + PV MFMAs dropped; pack kept live).
// MODE 4 = no staging (all DMA dropped; waits/barriers kept; stale LDS).
// Ablation dispatches write g_opart/g_ml with garbage; MODE 0 then fully
// overwrites every byte -> pipeline output unchanged.
__device__ __forceinline__ f16x8 pack_pfrag(const float* p, int h) {
    union PK { u32 u; f16x2 h2; } t0, t1, t2, t3;
    t0.h2 = f16x2{(f16)p[0], (f16)p[1]};
    t1.h2 = f16x2{(f16)p[2], (f16)p[3]};
    t2.h2 = f16x2{(f16)p[4], (f16)p[5]};
    t3.h2 = f16x2{(f16)p[6], (f16)p[7]};
    u32 sa = __shfl_xor(t0.u, 32, 64);
    u32 sb = __shfl_xor(t1.u, 32, 64);
    u32 sc = __shfl_xor(t2.u, 32, 64);
    u32 sd = __shfl_xor(t3.u, 32, 64);
    union RW { u32 w[4]; f16x8 v; } r;
    r.w[0] = h ? sc : t0.u;
    r.w[1] = h ? sd : t1.u;
    r.w[2] = h ? t2.u : sa;
    r.w[3] = h ? t3.u : sb;
    return r.v;
}
__device__ __forceinline__ void keep_frag(const f16x8& a, const f16x8& b) {
    union { f16x8 v; u32 w[4]; } ka, kb;
    ka.v = a; kb.v = b;
    asm volatile("" :: "v"(ka.w[0]), "v"(ka.w[1]), "v"(ka.w[2]), "v"(ka.w[3]),
                       "v"(kb.w[0]), "v"(kb.w[1]), "v"(kb.w[2]), "v"(kb.w[3]));
}

template<int MODE>
__global__ __launch_bounds__(256, 2) void k_attn_t() {
    __shared__ __align__(16) f16 smem[32768];   // 64 KB
    f16* kbuf = smem;            // 2 slots x 8192 halves
    f16* vbuf = smem + 16384;    // 2 slots x 8192 halves

    int bid = blockIdx.x;
    int x8 = bid & 7;
    int n = x8 >> 1, jhi = x8 & 1;
    int rest = bid >> 3;
    int jlo = rest & 1;
    int i0 = (rest >> 1) * 128;
    int jq = jhi * 2 + jlo;
    int tid = threadIdx.x, w = tid >> 6, lane = tid & 63;
    int j5 = lane & 31, h = lane >> 5;

    const f16* Qb = g_q + n * CHW;
    const f16* Kb = g_k + n * CHW;
    const f16* Vb = g_v + n * CHW;

    f16x8 qf[16];
    {
        const f16* qrow = Qb + (i0 + w * 32 + j5) * C_DIM + h * 8;
#pragma unroll
        for (int ck = 0; ck < 16; ++ck)
            qf[ck] = *(const f16x8*)(qrow + ck * 16);
    }

    int k_lane = h * 256 + j5 * 8;
    int v_lane = h * 2048 + j5 * 8;

    const f16* ksrc = Kb + (jq * 1024 + j5) * C_DIM + (w * 2 + h) * 8;
    const f16* vsrc = Vb + tid * HW + jq * 1024;
    int dst_w = w * 512;

    f32x16 o_acc[8];
#pragma unroll
    for (int ct = 0; ct < 8; ++ct)
#pragma unroll
        for (int r = 0; r < 16; ++r) o_acc[ct][r] = 0.f;

    float m_ = -1e30f, l_ = 0.f, al_prev = 1.f;
    f16x8 pf0 = {}, pf1 = {};

    // prologue: stage K(0); full drain; publish
    if constexpr (MODE != 4) {
#pragma unroll
        for (int s = 0; s < 4; ++s) gl2lds16(ksrc + s * 64, kbuf + s * 2048 + dst_w);
    }
    ksrc += 32 * C_DIM;
    asm volatile("s_waitcnt vmcnt(0)" ::: "memory");
    __builtin_amdgcn_s_barrier();
    __builtin_amdgcn_sched_barrier(0);

    for (int it = 0; it < 31; ++it) {
        int kcur = it & 1;
        if constexpr (MODE != 4) {
#pragma unroll
            for (int s = 0; s < 4; ++s)
                gl2lds16(ksrc + s * 64, kbuf + (kcur ^ 1) * 8192 + s * 2048 + dst_w);
        }
        ksrc += 32 * C_DIM;
        __builtin_amdgcn_sched_barrier(0);
        if constexpr (MODE != 4) {
#pragma unroll
            for (int s = 0; s < 4; ++s)
                gl2lds16(vsrc + s * 8, vbuf + kcur * 8192 + s * 2048 + dst_w);
        }
        vsrc += 32;
        __builtin_amdgcn_sched_barrier(0);

        // ---- Phase A: S^T(it) ----
        const f16* kb = kbuf + kcur * 8192 + k_lane;
        f32x16 sa, sb;
#pragma unroll
        for (int r = 0; r < 16; ++r) { sa[r] = 0.f; sb[r] = 0.f; }
        __builtin_amdgcn_s_setprio(1);
#pragma unroll
        for (int ck = 0; ck < 16; ++ck) {
            f16x8 kf = *(const f16x8*)(kb + ck * 512);
            if (ck & 1) sb = __builtin_amdgcn_mfma_f32_32x32x16_f16(kf, qf[ck], sb, 0, 0, 0);
            else        sa = __builtin_amdgcn_mfma_f32_32x32x16_f16(kf, qf[ck], sa, 0, 0, 0);
        }
        __builtin_amdgcn_s_setprio(0);
        f32x16 st;
#pragma unroll
        for (int r = 0; r < 16; ++r) st[r] = sa[r] + sb[r];

        asm volatile("s_waitcnt vmcnt(8)" ::: "memory");
        __builtin_amdgcn_s_barrier();
        __builtin_amdgcn_sched_barrier(0);

        // ---- Phase B: PV(it-1) ----
        if constexpr (MODE != 3) {
            if (it > 0) {
                if (__any(al_prev < 1.f)) {
#pragma unroll
                    for (int ct = 0; ct < 8; ++ct)
#pragma unroll
                        for (int r = 0; r < 16; ++r) o_acc[ct][r] *= al_prev;
                }
                const f16* vb = vbuf + (kcur ^ 1) * 8192 + v_lane;
                __builtin_amdgcn_s_setprio(1);
#pragma unroll
                for (int ct = 0; ct < 8; ++ct) {
                    f16x8 v0 = *(const f16x8*)(vb + ct * 256);
                    f16x8 v1 = *(const f16x8*)(vb + 4096 + ct * 256);
                    o_acc[ct] = __builtin_amdgcn_mfma_f32_32x32x16_f16(v0, pf0, o_acc[ct], 0, 0, 0);
                    o_acc[ct] = __builtin_amdgcn_mfma_f32_32x32x16_f16(v1, pf1, o_acc[ct], 0, 0, 0);
                }
                __builtin_amdgcn_s_setprio(0);
            }
        }

        // ---- softmax ----
        if constexpr (MODE == 1) {
#pragma unroll
            for (int r = 0; r < 16; ++r) asm volatile("" :: "v"(st[r]));
            m_ = fmaxf(m_, st[0] * 1e-30f);
            l_ += 1.f;
        } else {
            float mx0 = fmaxf(fmaxf(st[0], st[1]), fmaxf(st[2], st[3]));
            float mx1 = fmaxf(fmaxf(st[4], st[5]), fmaxf(st[6], st[7]));
            float mx2 = fmaxf(fmaxf(st[8], st[9]), fmaxf(st[10], st[11]));
            float mx3 = fmaxf(fmaxf(st[12], st[13]), fmaxf(st[14], st[15]));
            float smax = fmaxf(fmaxf(mx0, mx1), fmaxf(mx2, mx3));
            smax = fmaxf(smax, __shfl_xor(smax, 32, 64));
            float mq = __builtin_ceilf(smax * 0.125f) * 8.f;
            float mn = fmaxf(m_, mq);
            float al = __builtin_amdgcn_exp2f((m_ - mn) * L2E);
            float nl = -mn * L2E;
            float p[16];
#pragma unroll
            for (int r = 0; r < 16; ++r)
                p[r] = __builtin_amdgcn_exp2f(st[r] * L2E + nl);
            float a0 = (p[0] + p[1]) + (p[2] + p[3]);
            float a1 = (p[4] + p[5]) + (p[6] + p[7]);
            float a2 = (p[8] + p[9]) + (p[10] + p[11]);
            float a3 = (p[12] + p[13]) + (p[14] + p[15]);
            float rs = (a0 + a1) + (a2 + a3);
            m_ = mn;
            l_ = l_ * al + rs;
            al_prev = al;
            pf0 = pack_pfrag(p, h);
            pf1 = pack_pfrag(p + 8, h);
            if constexpr (MODE == 3) keep_frag(pf0, pf1);
        }

        asm volatile("s_waitcnt vmcnt(4)" ::: "memory");
        __builtin_amdgcn_s_barrier();
        __builtin_amdgcn_sched_barrier(0);
    }

    // ---- peeled it=31 ----
    {
        if constexpr (MODE != 4) {
#pragma unroll
            for (int s = 0; s < 4; ++s)
                gl2lds16(vsrc + s * 8, vbuf + 8192 + s * 2048 + dst_w);
        }
        __builtin_amdgcn_sched_barrier(0);

        const f16* kb = kbuf + 8192 + k_lane;
        f32x16 sa, sb;
#pragma unroll
        for (int r = 0; r < 16; ++r) { sa[r] = 0.f; sb[r] = 0.f; }
        __builtin_amdgcn_s_setprio(1);
#pragma unroll
        for (int ck = 0; ck < 16; ++ck) {
            f16x8 kf = *(const f16x8*)(kb + ck * 512);
            if (ck & 1) sb = __builtin_amdgcn_mfma_f32_32x32x16_f16(kf, qf[ck], sb, 0, 0, 0);
            else        sa = __builtin_amdgcn_mfma_f32_32x32x16_f16(kf, qf[ck], sa, 0, 0, 0);
        }
        __builtin_amdgcn_s_setprio(0);
        f32x16 st;
#pragma unroll
        for (int r = 0; r < 16; ++r) st[r] = sa[r] + sb[r];

        asm volatile("s_waitcnt vmcnt(4)" ::: "memory");
        __builtin_amdgcn_s_barrier();
        __builtin_amdgcn_sched_barrier(0);

        if constexpr (MODE != 3) {
            if (__any(al_prev < 1.f)) {
#pragma unroll
                for (int ct = 0; ct < 8; ++ct)
#pragma unroll
                    for (int r = 0; r < 16; ++r) o_acc[ct][r] *= al_prev;
            }
            const f16* vb = vbuf + v_lane;
            __builtin_amdgcn_s_setprio(1);
#pragma unroll
            for (int ct = 0; ct < 8; ++ct) {
                f16x8 v0 = *(const f16x8*)(vb + ct * 256);
                f16x8 v1 = *(const f16x8*)(vb + 4096 + ct * 256);
                o_acc[ct] = __builtin_amdgcn_mfma_f32_32x32x16_f16(v0, pf0, o_acc[ct], 0, 0, 0);
                o_acc[ct] = __builtin_amdgcn_mfma_f32_32x32x16_f16(v1, pf1, o_acc[ct], 0, 0, 0);
            }
            __builtin_amdgcn_s_setprio(0);
        }

        if constexpr (MODE == 1) {
#pragma unroll
            for (int r = 0; r < 16; ++r) asm volatile("" :: "v"(st[r]));
            m_ = fmaxf(m_, st[0] * 1e-30f);
            l_ += 1.f;
        } else {
            float mx0 = fmaxf(fmaxf(st[0], st[1]), fmaxf(st[2], st[3]));
            float mx1 = fmaxf(fmaxf(st[4], st[5]), fmaxf(st[6], st[7]));
            float mx2 = fmaxf(fmaxf(st[8], st[9]), fmaxf(st[10], st[11]));
            float mx3 = fmaxf(fmaxf(st[12], st[13]), fmaxf(st[14], st[15]));
            float smax = fmaxf(fmaxf(mx0, mx1), fmaxf(mx2, mx3));
            smax = fmaxf(smax, __shfl_xor(smax, 32, 64));
            float mq = __builtin_ceilf(smax * 0.125f) * 8.f;
            float mn = fmaxf(m_, mq);
            float al = __builtin_amdgcn_exp2f((m_ - mn) * L2E);
            float nl = -mn * L2E;
            float p[16];
#pragma unroll
            for (int r = 0; r < 16; ++r)
                p[r] = __builtin_amdgcn_exp2f(st[r] * L2E + nl);
            float a0 = (p[0] + p[1]) + (p[2] + p[3]);
            float a1 = (p[4] + p[5]) + (p[6] + p[7]);
            float a2 = (p[8] + p[9]) + (p[10] + p[11]);
            float a3 = (p[12] + p[13]) + (p[14] + p[15]);
            float rs = (a0 + a1) + (a2 + a3);
            m_ = mn;
            l_ = l_ * al + rs;
            al_prev = al;
            pf0 = pack_pfrag(p, h);
            pf1 = pack_pfrag(p + 8, h);
            if constexpr (MODE == 3) keep_frag(pf0, pf1);
        }

        asm volatile("s_waitcnt vmcnt(0)" ::: "memory");
        __builtin_amdgcn_s_barrier();
        __builtin_amdgcn_sched_barrier(0);

        if constexpr (MODE != 3) {
            if (__any(al_prev < 1.f)) {
#pragma unroll
                for (int ct = 0; ct < 8; ++ct)
#pragma unroll
                    for (int r = 0; r < 16; ++r) o_acc[ct][r] *= al_prev;
            }
            const f16* vb = vbuf + 8192 + v_lane;
#pragma unroll
            for (int ct = 0; ct < 8; ++ct) {
                f16x8 v0 = *(const f16x8*)(vb + ct * 256);
                f16x8 v1 = *(const f16x8*)(vb + 4096 + ct * 256);
                o_acc[ct] = __builtin_amdgcn_mfma_f32_32x32x16_f16(v0, pf0, o_acc[ct], 0, 0, 0);
                o_acc[ct] = __builtin_amdgcn_mfma_f32_32x32x16_f16(v1, pf1, o_acc[ct], 0, 0, 0);
            }
        }
    }

    l_ += __shfl_xor(l_, 32, 64);

    int slot = jq * 4 + n;
    int i_out = i0 + w * 32 + j5;
    if (h == 0) {
        g_ml[(slot * 2 + 0) * HW + i_out] = m_;
        g_ml[(slot * 2 + 1) * HW + i_out] = l_;
    }
    float inv = (l_ > 1e-30f) ? 1.f / l_ : 0.f;
    f16* ob = g_opart + slot * CHW + i_out;
#pragma unroll
    for (int ct = 0; ct < 8; ++ct) {
        int cbase = ct * 32 + 4 * h;
#pragma unroll
        for (int r = 0; r < 16; ++r) {
            int c = cbase + (r & 3) + 8 * (r >> 2);
            ob[c * HW] = (f16)(o_acc[ct][r] * inv);
        }
    }
}

// ---------------- kernel 4: merge 4 j-quarters + residual + store (8-wide) ----------------
__global__ __launch_bounds__(256) void k_combine(
    const void* __restrict__ xv, const void* __restrict__ gv, void* __restrict__ outv)
{
    int mode = probe_mode(xv);
    float gam = fin0(mode ? ((const float*)gv)[0] : bf2f(((const ushort_t*)gv)[0]));
    int n = blockIdx.y;
    int off = blockIdx.x * 2048 + threadIdx.x * 8;   // 8 consecutive i, same c
    int i = off & (HW - 1);

    u16x8 op[4];
    float ms[4][8], ls[4][8];
#pragma unroll
    for (int s = 0; s < 4; ++s) {
        int slot = s * 4 + n;
        op[s] = *(const u16x8*)((const ushort_t*)g_opart + slot * CHW + off);
        float4 mA = *(const float4*)&g_ml[(slot * 2 + 0) * HW + i];
        float4 mB = *(const float4*)&g_ml[(slot * 2 + 0) * HW + i + 4];
        float4 lA = *(const float4*)&g_ml[(slot * 2 + 1) * HW + i];
        float4 lB = *(const float4*)&g_ml[(slot * 2 + 1) * HW + i + 4];
        ms[s][0]=mA.x; ms[s][1]=mA.y; ms[s][2]=mA.z; ms[s][3]=mA.w;
        ms[s][4]=mB.x; ms[s][5]=mB.y; ms[s][6]=mB.z; ms[s][7]=mB.w;
        ls[s][0]=lA.x; ls[s][1]=lA.y; ls[s][2]=lA.z; ls[s][3]=lA.w;
        ls[s][4]=lB.x; ls[s][5]=lB.y; ls[s][6]=lB.z; ls[s][7]=lB.w;
    }

    float o[8];
#pragma unroll
    for (int e = 0; e < 8; ++e) {
        float m = fmaxf(fmaxf(ms[0][e], ms[1][e]), fmaxf(ms[2][e], ms[3][e]));
        float num = 0.f, den = 0.f;
#pragma unroll
        for (int s = 0; s < 4; ++s) {
            float wgt = __builtin_amdgcn_exp2f((ms[s][e] - m) * L2E) * ls[s][e];
            union { ushort_t u; f16 h; } cv; cv.u = (ushort_t)op[s][e];
            num += wgt * (float)cv.h;
            den += wgt;
        }
        o[e] = (den > 1e-30f) ? num / den : 0.f;
    }

    if (mode == 0) {
        u16x8 xp = *(const u16x8*)((const ushort_t*)xv + n * CHW + off);
        u16x8 res;
#pragma unroll
        for (int e = 0; e < 8; ++e)
            res[e] = f2bf(fin0(bf2f((ushort_t)xp[e]) + gam * o[e]));
        *(u16x8*)((ushort_t*)outv + n * CHW + off) = res;
    } else {
        const float* xb = (const float*)xv + n * CHW + off;
        float* outb = (float*)outv + n * CHW + off;
        float4 xA = *(const float4*)xb;
        float4 xB = *(const float4*)(xb + 4);
        float4 rA, rB;
        rA.x = fin0(xA.x + gam * o[0]); rA.y = fin0(xA.y + gam * o[1]);
        rA.z = fin0(xA.z + gam * o[2]); rA.w = fin0(xA.w + gam * o[3]);
        rB.x = fin0(xB.x + gam * o[4]); rB.y = fin0(xB.y + gam * o[5]);
        rB.z = fin0(xB.z + gam * o[6]); rB.w = fin0(xB.w + gam * o[7]);
        *(float4*)outb = rA;
        *(float4*)(outb + 4) = rB;
    }
}

extern "C" void kernel_launch(void* const* d_in, const int* in_sizes, int n_in,
                              void* d_out, int out_size, void* d_ws, size_t ws_size,
                              hipStream_t stream) {
    (void)d_ws; (void)ws_size;
    bool ok = (n_in == 8) &&
              in_sizes[0] == 4 * CHW &&
              in_sizes[1] == C_DIM * C_DIM && in_sizes[2] == C_DIM &&
              in_sizes[3] == C_DIM * C_DIM && in_sizes[4] == C_DIM &&
              in_sizes[5] == C_DIM * C_DIM && in_sizes[6] == C_DIM &&
              in_sizes[7] == 1 && out_size == 4 * CHW;
    if (!ok) {
        hipLaunchKernelGGL(k_sentinel, dim3((out_size + 255) / 256), dim3(256), 0, stream,
                           (ushort_t*)d_out, out_size);
        return;
    }
    hipLaunchKernelGGL(k_transpose, dim3(64, 4, 4), dim3(256), 0, stream, d_in[0]);
    hipLaunchKernelGGL(k_proj, dim3(32, 6, 4), dim3(256), 0, stream,
                       d_in[1], d_in[2], d_in[3], d_in[4], d_in[5], d_in[6]);
    // --- one-time ablation dispatches (outputs fully overwritten by MODE 0) ---
    hipLaunchKernelGGL(k_attn_t<1>, dim3(512), dim3(256), 0, stream);   // no softmax
    hipLaunchKernelGGL(k_attn_t<3>, dim3(512), dim3(256), 0, stream);   // no PV phase
    hipLaunchKernelGGL(k_attn_t<4>, dim3(512), dim3(256), 0, stream);   // no staging
    // --- real attention ---
    hipLaunchKernelGGL(k_attn_t<0>, dim3(512), dim3(256), 0, stream);
    hipLaunchKernelGGL(k_combine, dim3(CHW / 2048, 4), dim3(256), 0, stream,
                       d_in[0], d_in[7], d_out);
}

// Round 11
// 288.623 us; speedup vs baseline: 1.6000x; 1.6000x over previous
//
#include <hip/hip_runtime.h>

typedef unsigned short ushort_t;
typedef unsigned int u32;
typedef _Float16 f16;
typedef f16 f16x8 __attribute__((ext_vector_type(8)));
typedef f16 f16x2 __attribute__((ext_vector_type(2)));
typedef ushort_t u16x8 __attribute__((ext_vector_type(8)));
typedef float f32x4 __attribute__((ext_vector_type(4)));
typedef float f32x16 __attribute__((ext_vector_type(16)));

#define C_DIM 256
#define HW 4096
#define CHW (C_DIM*HW)
#define L2E 1.4426950408889634f

// Device-global scratch. Internal pipeline f16.
__device__ __align__(16) f16 g_xbT[4 * CHW];
__device__ __align__(16) f16 g_q[4 * CHW];
__device__ __align__(16) f16 g_k[4 * CHW];
__device__ __align__(16) f16 g_v[4 * CHW];
__device__ __align__(16) f16 g_opart[16 * CHW];   // [slot=jq*4+n][c][i] normalized O^T
__device__ __align__(16) float g_ml[16 * 2 * HW]; // [slot][{m,l}][i]

__device__ __forceinline__ float bf2f(ushort_t h) {
    union { u32 u; float f; } v; v.u = ((u32)h) << 16; return v.f;
}
__device__ __forceinline__ ushort_t f2bf(float f) {
    union { float f; u32 u; } v; v.f = f;
    u32 r = v.u + 0x7FFF + ((v.u >> 16) & 1);
    return (ushort_t)(r >> 16);
}
__device__ __forceinline__ float fin0(float v) {
    return (v > -1e30f && v < 1e30f) ? v : 0.f;
}
__device__ __forceinline__ f16 sf16(float v) {
    return (f16)((v > -1e4f && v < 1e4f) ? v : 0.f);
}
__device__ __forceinline__ void gl2lds16(const f16* g, f16* l) {
    __builtin_amdgcn_global_load_lds(
        (const __attribute__((address_space(1))) u32*)g,
        (__attribute__((address_space(3))) u32*)l, 16, 0, 0);
}
// Local dtype probe: read 64 halves as bf16; f32-misread low-halves decode huge.
__device__ __forceinline__ int probe_mode(const void* p) {
    int lane = threadIdx.x & 63;
    float v = fabsf(bf2f(((const ushort_t*)p)[lane]));
    v = (v < 1e6f) ? v : 1e6f;
#pragma unroll
    for (int d = 1; d < 64; d <<= 1) v += __shfl_xor(v, d, 64);
    return (v * (1.f / 64.f) > 100.f) ? 1 : 0;
}

__global__ void k_sentinel(ushort_t* out, int n) {
    int i = blockIdx.x * 256 + threadIdx.x;
    if (i < n) out[i] = f2bf(777.f);
}

// ---------------- kernel 1: x (N,C,HW) -> g_xbT f16 (N,HW,C) ----------------
__global__ __launch_bounds__(256) void k_transpose(const void* __restrict__ xv) {
    __shared__ f16 t[64][66];
    int mode = probe_mode(xv);
    int n = blockIdx.z, c0 = blockIdx.y * 64, l0 = blockIdx.x * 64;
    int tid = threadIdx.x;
    f16* ob = g_xbT + n * CHW;
    int lq = (tid & 15) * 4;
    int cl = tid >> 4;
    if (mode == 0) {
        const ushort_t* xb = (const ushort_t*)xv + n * CHW;
#pragma unroll
        for (int p = 0; p < 4; ++p) {
            int c = cl + 16 * p;
            ushort4 v = *(const ushort4*)(xb + (c0 + c) * HW + l0 + lq);
            t[lq + 0][c] = sf16(bf2f(v.x));
            t[lq + 1][c] = sf16(bf2f(v.y));
            t[lq + 2][c] = sf16(bf2f(v.z));
            t[lq + 3][c] = sf16(bf2f(v.w));
        }
    } else {
        const float* xb = (const float*)xv + n * CHW;
#pragma unroll
        for (int p = 0; p < 4; ++p) {
            int c = cl + 16 * p;
            float4 v = *(const float4*)(xb + (c0 + c) * HW + l0 + lq);
            t[lq + 0][c] = sf16(v.x);
            t[lq + 1][c] = sf16(v.y);
            t[lq + 2][c] = sf16(v.z);
            t[lq + 3][c] = sf16(v.w);
        }
    }
    __syncthreads();
    int c2 = (tid & 31) * 2;
    int lr = tid >> 5;
#pragma unroll
    for (int p = 0; p < 8; ++p) {
        int l = lr + 8 * p;
        u32 pair = *(const u32*)&t[l][c2];
        *(u32*)(ob + (l0 + l) * C_DIM + c0 + c2) = pair;
    }
}

// ---------------- kernel 2: projections (f16 MFMA) ----------------
__global__ __launch_bounds__(256) void k_proj(
    const void* __restrict__ Wq, const void* __restrict__ bq,
    const void* __restrict__ Wk, const void* __restrict__ bk,
    const void* __restrict__ Wv, const void* __restrict__ bv)
{
    __shared__ __align__(16) f16 lds_x[128 * 64];
    __shared__ __align__(16) f16 lds_w[128 * 64];
    int l0 = blockIdx.x * 128;
    int og0 = blockIdx.y * 128;
    int n = blockIdx.z;
    int mat = og0 >> 8;       // 0=q,1=k,2=v
    int om0 = og0 & 255;
    const void* W = (mat == 0) ? Wq : (mat == 1) ? Wk : Wv;
    const void* bias = (mat == 0) ? bq : (mat == 1) ? bk : bv;
    int mode = probe_mode(W);
    int tid = threadIdx.x, w = tid >> 6, lane = tid & 63;
    int quad = lane >> 4, l16 = lane & 15;
    const f16* xb = g_xbT + n * CHW;

    f32x4 acc[2][8];
#pragma unroll
    for (int a = 0; a < 2; a++)
#pragma unroll
        for (int b = 0; b < 8; b++) acc[a][b] = f32x4{0.f, 0.f, 0.f, 0.f};

    for (int ch = 0; ch < 4; ++ch) {
        int cc0 = ch * 64;
        f16x8 xs[4], wsr[4];
#pragma unroll
        for (int ti = 0; ti < 4; ++ti) {
            int s = (w * 4 + ti) * 64 + lane;
            int row = s >> 3, gp = s & 7;
            xs[ti] = *(const f16x8*)(xb + (l0 + row) * C_DIM + cc0 + gp * 8);
            f16x8 h;
            if (mode == 0) {
                u16x8 wv = *(const u16x8*)((const ushort_t*)W + (om0 + row) * C_DIM + cc0 + gp * 8);
#pragma unroll
                for (int e = 0; e < 8; e++) h[e] = sf16(bf2f(wv[e]));
            } else {
                const float* wf = (const float*)W + (om0 + row) * C_DIM + cc0 + gp * 8;
#pragma unroll
                for (int e = 0; e < 8; e++) h[e] = sf16(wf[e]);
            }
            wsr[ti] = h;
        }
        __syncthreads();
#pragma unroll
        for (int ti = 0; ti < 4; ++ti) {
            int s = (w * 4 + ti) * 64 + lane;
            int row = s >> 3, gp = s & 7;
            int pos = gp ^ (row & 7);
            *(f16x8*)(lds_x + (row * 8 + pos) * 8) = xs[ti];
            *(f16x8*)(lds_w + (row * 8 + pos) * 8) = wsr[ti];
        }
        __syncthreads();
#pragma unroll
        for (int ks = 0; ks < 2; ++ks) {
            f16x8 af[2];
#pragma unroll
            for (int mt = 0; mt < 2; ++mt) {
                int row = w * 32 + mt * 16 + l16;
                int g = ks * 4 + quad;
                int pos = g ^ (row & 7);
                af[mt] = *(const f16x8*)(lds_x + (row * 8 + pos) * 8);
            }
#pragma unroll
            for (int nt = 0; nt < 8; ++nt) {
                int rowo = nt * 16 + l16;
                int g = ks * 4 + quad;
                int pos = g ^ (rowo & 7);
                f16x8 bfv = *(const f16x8*)(lds_w + (rowo * 8 + pos) * 8);
                if (mat < 2) {
                    acc[0][nt] = __builtin_amdgcn_mfma_f32_16x16x32_f16(af[0], bfv, acc[0][nt], 0, 0, 0);
                    acc[1][nt] = __builtin_amdgcn_mfma_f32_16x16x32_f16(af[1], bfv, acc[1][nt], 0, 0, 0);
                } else {
                    acc[0][nt] = __builtin_amdgcn_mfma_f32_16x16x32_f16(bfv, af[0], acc[0][nt], 0, 0, 0);
                    acc[1][nt] = __builtin_amdgcn_mfma_f32_16x16x32_f16(bfv, af[1], acc[1][nt], 0, 0, 0);
                }
            }
        }
        __syncthreads();
    }

    auto loadb = [&](int i) -> float {
        return mode ? ((const float*)bias)[i] : bf2f(((const ushort_t*)bias)[i]);
    };
    if (mat < 2) {
        f16* T = ((mat == 0) ? g_q : g_k) + n * CHW;
        float bvv[8];
#pragma unroll
        for (int nt = 0; nt < 8; nt++) bvv[nt] = loadb(om0 + nt * 16 + l16);
#pragma unroll
        for (int mt = 0; mt < 2; mt++)
#pragma unroll
            for (int nt = 0; nt < 8; nt++)
#pragma unroll
                for (int r = 0; r < 4; r++) {
                    int l = l0 + w * 32 + mt * 16 + quad * 4 + r;
                    int o = om0 + nt * 16 + l16;
                    T[l * C_DIM + o] = sf16(acc[mt][nt][r] + bvv[nt]);
                }
    } else {
        f16* T = g_v + n * CHW;
#pragma unroll
        for (int mt = 0; mt < 2; mt++)
#pragma unroll
            for (int nt = 0; nt < 8; nt++)
#pragma unroll
                for (int r = 0; r < 4; r++) {
                    int o = om0 + nt * 16 + quad * 4 + r;
                    int l = l0 + w * 32 + mt * 16 + l16;
                    T[o * HW + l] = sf16(acc[mt][nt][r] + loadb(o));
                }
    }
}

// ---------------- kernel 3: flash attention, c-split occupancy build ----------
// Ablation (R10) showed additive phases (sm 27 + pv 27 + stage 27 + base 20 us)
// = latency-serial at 2 waves/SIMD (o_acc 128 + operands ~= 256 regs). Fix:
// wave tile 32i x 128c -> o_acc 64 regs, resident Q-half 32 regs, est ~160 regs
// -> launch_bounds(256,3) caps 170 -> 3 waves/SIMD. Block = 64i x 256c (4 waves:
// 2 i-chunks x 2 c-halves), grid 1024. S NOT duplicated: each wave computes the
// c-half partial S (8 MFMAs); partials summed via 16KB LDS exchange at the
// existing mid barrier (identical lane layouts -> elementwise add; 2-way bank
// aliasing = free). K,V single-buffered, split-drain counted vmcnt:
//   start:  vmcnt(4) drains K(it)   [K issued mid prev iter]
//   mid:    vmcnt(0) drains V(it-1) [V issued end prev iter] + lgkm for xbuf
//   end:    barrier only; then issue V(it)
// LDS 48KB (K16+V16+X16) -> 3 blocks/CU. Slots/combine unchanged.
__device__ __forceinline__ f16x8 pack_pfrag(const float* p, int h) {
    // p[r] holds P^T[j = (r&3)+8*(r>>2)+4*h][i = lane&31] for one 16-j chunk.
    union PK { u32 u; f16x2 h2; } t0, t1, t2, t3;
    t0.h2 = f16x2{(f16)p[0], (f16)p[1]};
    t1.h2 = f16x2{(f16)p[2], (f16)p[3]};
    t2.h2 = f16x2{(f16)p[4], (f16)p[5]};
    t3.h2 = f16x2{(f16)p[6], (f16)p[7]};
    u32 sa = __shfl_xor(t0.u, 32, 64);
    u32 sb = __shfl_xor(t1.u, 32, 64);
    u32 sc = __shfl_xor(t2.u, 32, 64);
    u32 sd = __shfl_xor(t3.u, 32, 64);
    union RW { u32 w[4]; f16x8 v; } r;
    r.w[0] = h ? sc : t0.u;
    r.w[1] = h ? sd : t1.u;
    r.w[2] = h ? t2.u : sa;
    r.w[3] = h ? t3.u : sb;
    return r.v;
}

__global__ __launch_bounds__(256, 3) void k_attn() {
    __shared__ __align__(16) f16 smem[24576];      // 48 KB
    f16* kbuf = smem;                               // 8192 halves: K[j=32][256c], granule cg*32+j
    f16* vbuf = smem + 8192;                        // 8192 halves: V[c=256][32j], granule jg*256+c
    float* xbuf = (float*)(smem + 16384);           // 4096 f32: 4 slots x 1024 (S-partial exchange)

    int bid = blockIdx.x;
    int n = bid & 3;
    int jq = (bid >> 2) & 3;
    int i0 = (bid >> 4) * 64;
    int tid = threadIdx.x, w = tid >> 6, lane = tid & 63;
    int j5 = lane & 31, h = lane >> 5;
    int ic = w >> 1, ch = w & 1;

    const f16* Qb = g_q + n * CHW;
    const f16* Kb = g_k + n * CHW;
    const f16* Vb = g_v + n * CHW;

    // resident Q c-half fragment: B operand (i = lane&31, k = h*8+e), 32 VGPR
    f16x8 qf[8];
    {
        const f16* qrow = Qb + (i0 + ic * 32 + j5) * C_DIM + ch * 128 + h * 8;
#pragma unroll
        for (int ck = 0; ck < 8; ++ck)
            qf[ck] = *(const f16x8*)(qrow + ck * 16);
    }

    int k_lane = ch * 4096 + h * 256 + j5 * 8;      // + ck*512 : cg = ch*16 + ck*2 + h, j = j5
    int v_lane = h * 2048 + ch * 1024 + j5 * 8;     // + js*4096 + ct*256 : c = ch*128+ct*32+j5
    float* x_my = xbuf + (ic * 2 + ch) * 1024 + lane * 16;
    const float* x_peer = xbuf + (ic * 2 + (ch ^ 1)) * 1024 + lane * 16;

    const f16* ksrc = Kb + (jq * 1024 + j5) * C_DIM + (w * 2 + h) * 8;
    const f16* vsrc = Vb + tid * HW + jq * 1024;
    int dst_w = w * 512;

    f32x16 o_acc[4];
#pragma unroll
    for (int ct = 0; ct < 4; ++ct)
#pragma unroll
        for (int r = 0; r < 16; ++r) o_acc[ct][r] = 0.f;

    float m_ = -1e30f, l_ = 0.f, al_prev = 1.f;
    f16x8 pf0 = {}, pf1 = {};

    // prologue: stage K(0); full drain; publish
#pragma unroll
    for (int s = 0; s < 4; ++s) gl2lds16(ksrc + s * 64, kbuf + s * 2048 + dst_w);
    ksrc += 32 * C_DIM;
    asm volatile("s_waitcnt vmcnt(0)" ::: "memory");
    __builtin_amdgcn_s_barrier();
    __builtin_amdgcn_sched_barrier(0);

    for (int it = 0; it < 32; ++it) {
        if (it > 0) {
            // drain K(it) (4 oldest); V(it-1) stays in flight
            asm volatile("s_waitcnt vmcnt(4)" ::: "memory");
            __builtin_amdgcn_s_barrier();
            __builtin_amdgcn_sched_barrier(0);
        }

        // ---- Phase A: partial S^T over this wave's c-half (8 MFMAs) ----
        const f16* kb = kbuf + k_lane;
        f32x16 sp;
#pragma unroll
        for (int r = 0; r < 16; ++r) sp[r] = 0.f;
        __builtin_amdgcn_s_setprio(1);
#pragma unroll
        for (int ck = 0; ck < 8; ++ck) {
            f16x8 kf = *(const f16x8*)(kb + ck * 512);
            sp = __builtin_amdgcn_mfma_f32_32x32x16_f16(kf, qf[ck], sp, 0, 0, 0);
        }
        __builtin_amdgcn_s_setprio(0);
        // publish partial to exchange buffer (identical lane layout both halves)
#pragma unroll
        for (int q = 0; q < 4; ++q)
            *(f32x4*)(x_my + q * 4) = f32x4{sp[q*4+0], sp[q*4+1], sp[q*4+2], sp[q*4+3]};
        asm volatile("s_waitcnt lgkmcnt(0)" ::: "memory");

        // mid: V(it-1) landed; xbuf published; kbuf reads done
        asm volatile("s_waitcnt vmcnt(0)" ::: "memory");
        __builtin_amdgcn_s_barrier();
        __builtin_amdgcn_sched_barrier(0);

        // issue K(it+1) into the (now-free) single K buffer
        if (it < 31) {
#pragma unroll
            for (int s = 0; s < 4; ++s)
                gl2lds16(ksrc + s * 64, kbuf + s * 2048 + dst_w);
            ksrc += 32 * C_DIM;
        }
        __builtin_amdgcn_sched_barrier(0);

        // ---- Phase B: PV(it-1) on this wave's c-half ----
        if (it > 0) {
            if (__any(al_prev < 1.f)) {
#pragma unroll
                for (int ct = 0; ct < 4; ++ct)
#pragma unroll
                    for (int r = 0; r < 16; ++r) o_acc[ct][r] *= al_prev;
            }
            const f16* vb = vbuf + v_lane;
            __builtin_amdgcn_s_setprio(1);
#pragma unroll
            for (int ct = 0; ct < 4; ++ct) {
                f16x8 v0 = *(const f16x8*)(vb + ct * 256);
                f16x8 v1 = *(const f16x8*)(vb + 4096 + ct * 256);
                o_acc[ct] = __builtin_amdgcn_mfma_f32_32x32x16_f16(v0, pf0, o_acc[ct], 0, 0, 0);
                o_acc[ct] = __builtin_amdgcn_mfma_f32_32x32x16_f16(v1, pf1, o_acc[ct], 0, 0, 0);
            }
            __builtin_amdgcn_s_setprio(0);
        }

        // ---- exchange-add + softmax (identical in both c-half waves) ----
        f32x16 st;
#pragma unroll
        for (int q = 0; q < 4; ++q) {
            f32x4 pp = *(const f32x4*)(x_peer + q * 4);
#pragma unroll
            for (int e = 0; e < 4; ++e) st[q*4+e] = sp[q*4+e] + pp[e];
        }
        float mx0 = fmaxf(fmaxf(st[0], st[1]), fmaxf(st[2], st[3]));
        float mx1 = fmaxf(fmaxf(st[4], st[5]), fmaxf(st[6], st[7]));
        float mx2 = fmaxf(fmaxf(st[8], st[9]), fmaxf(st[10], st[11]));
        float mx3 = fmaxf(fmaxf(st[12], st[13]), fmaxf(st[14], st[15]));
        float smax = fmaxf(fmaxf(mx0, mx1), fmaxf(mx2, mx3));
        smax = fmaxf(smax, __shfl_xor(smax, 32, 64));
        float mq = __builtin_ceilf(smax * 0.125f) * 8.f;   // quantized max
        float mn = fmaxf(m_, mq);
        float al = __builtin_amdgcn_exp2f((m_ - mn) * L2E);
        float nl = -mn * L2E;
        float p[16];
#pragma unroll
        for (int r = 0; r < 16; ++r)
            p[r] = __builtin_amdgcn_exp2f(st[r] * L2E + nl);
        float a0 = (p[0] + p[1]) + (p[2] + p[3]);
        float a1 = (p[4] + p[5]) + (p[6] + p[7]);
        float a2 = (p[8] + p[9]) + (p[10] + p[11]);
        float a3 = (p[12] + p[13]) + (p[14] + p[15]);
        float rs = (a0 + a1) + (a2 + a3);   // per-half partial; cross-add deferred
        m_ = mn;
        l_ = l_ * al + rs;
        al_prev = al;
        pf0 = pack_pfrag(p, h);
        pf1 = pack_pfrag(p + 8, h);

        // end: vbuf + xbuf reads done -> safe to restage V
        __builtin_amdgcn_s_barrier();
        __builtin_amdgcn_sched_barrier(0);
#pragma unroll
        for (int s = 0; s < 4; ++s)
            gl2lds16(vsrc + s * 8, vbuf + s * 2048 + dst_w);
        vsrc += 32;
        __builtin_amdgcn_sched_barrier(0);
    }

    // ---- epilogue: PV(31) ----
    asm volatile("s_waitcnt vmcnt(0)" ::: "memory");
    __builtin_amdgcn_s_barrier();
    __builtin_amdgcn_sched_barrier(0);
    {
        if (__any(al_prev < 1.f)) {
#pragma unroll
            for (int ct = 0; ct < 4; ++ct)
#pragma unroll
                for (int r = 0; r < 16; ++r) o_acc[ct][r] *= al_prev;
        }
        const f16* vb = vbuf + v_lane;
#pragma unroll
        for (int ct = 0; ct < 4; ++ct) {
            f16x8 v0 = *(const f16x8*)(vb + ct * 256);
            f16x8 v1 = *(const f16x8*)(vb + 4096 + ct * 256);
            o_acc[ct] = __builtin_amdgcn_mfma_f32_32x32x16_f16(v0, pf0, o_acc[ct], 0, 0, 0);
            o_acc[ct] = __builtin_amdgcn_mfma_f32_32x32x16_f16(v1, pf1, o_acc[ct], 0, 0, 0);
        }
    }

    // complete the deferred cross-half l reduction
    l_ += __shfl_xor(l_, 32, 64);

    // ---- write partials ----
    int slot = jq * 4 + n;
    int i_out = i0 + ic * 32 + j5;
    if (h == 0 && ch == 0) {
        g_ml[(slot * 2 + 0) * HW + i_out] = m_;
        g_ml[(slot * 2 + 1) * HW + i_out] = l_;
    }
    float inv = (l_ > 1e-30f) ? 1.f / l_ : 0.f;
    f16* ob = g_opart + slot * CHW + i_out;
#pragma unroll
    for (int ct = 0; ct < 4; ++ct) {
        int cbase = ch * 128 + ct * 32 + 4 * h;
#pragma unroll
        for (int r = 0; r < 16; ++r) {
            int c = cbase + (r & 3) + 8 * (r >> 2);
            ob[c * HW] = (f16)(o_acc[ct][r] * inv);
        }
    }
}

// ---------------- kernel 4: merge 4 j-quarters + residual + store (8-wide) ----------------
__global__ __launch_bounds__(256) void k_combine(
    const void* __restrict__ xv, const void* __restrict__ gv, void* __restrict__ outv)
{
    int mode = probe_mode(xv);
    float gam = fin0(mode ? ((const float*)gv)[0] : bf2f(((const ushort_t*)gv)[0]));
    int n = blockIdx.y;
    int off = blockIdx.x * 2048 + threadIdx.x * 8;   // 8 consecutive i, same c
    int i = off & (HW - 1);

    u16x8 op[4];
    float ms[4][8], ls[4][8];
#pragma unroll
    for (int s = 0; s < 4; ++s) {
        int slot = s * 4 + n;
        op[s] = *(const u16x8*)((const ushort_t*)g_opart + slot * CHW + off);
        float4 mA = *(const float4*)&g_ml[(slot * 2 + 0) * HW + i];
        float4 mB = *(const float4*)&g_ml[(slot * 2 + 0) * HW + i + 4];
        float4 lA = *(const float4*)&g_ml[(slot * 2 + 1) * HW + i];
        float4 lB = *(const float4*)&g_ml[(slot * 2 + 1) * HW + i + 4];
        ms[s][0]=mA.x; ms[s][1]=mA.y; ms[s][2]=mA.z; ms[s][3]=mA.w;
        ms[s][4]=mB.x; ms[s][5]=mB.y; ms[s][6]=mB.z; ms[s][7]=mB.w;
        ls[s][0]=lA.x; ls[s][1]=lA.y; ls[s][2]=lA.z; ls[s][3]=lA.w;
        ls[s][4]=lB.x; ls[s][5]=lB.y; ls[s][6]=lB.z; ls[s][7]=lB.w;
    }

    float o[8];
#pragma unroll
    for (int e = 0; e < 8; ++e) {
        float m = fmaxf(fmaxf(ms[0][e], ms[1][e]), fmaxf(ms[2][e], ms[3][e]));
        float num = 0.f, den = 0.f;
#pragma unroll
        for (int s = 0; s < 4; ++s) {
            float wgt = __builtin_amdgcn_exp2f((ms[s][e] - m) * L2E) * ls[s][e];
            union { ushort_t u; f16 h; } cv; cv.u = (ushort_t)op[s][e];
            num += wgt * (float)cv.h;
            den += wgt;
        }
        o[e] = (den > 1e-30f) ? num / den : 0.f;
    }

    if (mode == 0) {
        u16x8 xp = *(const u16x8*)((const ushort_t*)xv + n * CHW + off);
        u16x8 res;
#pragma unroll
        for (int e = 0; e < 8; ++e)
            res[e] = f2bf(fin0(bf2f((ushort_t)xp[e]) + gam * o[e]));
        *(u16x8*)((ushort_t*)outv + n * CHW + off) = res;
    } else {
        const float* xb = (const float*)xv + n * CHW + off;
        float* outb = (float*)outv + n * CHW + off;
        float4 xA = *(const float4*)xb;
        float4 xB = *(const float4*)(xb + 4);
        float4 rA, rB;
        rA.x = fin0(xA.x + gam * o[0]); rA.y = fin0(xA.y + gam * o[1]);
        rA.z = fin0(xA.z + gam * o[2]); rA.w = fin0(xA.w + gam * o[3]);
        rB.x = fin0(xB.x + gam * o[4]); rB.y = fin0(xB.y + gam * o[5]);
        rB.z = fin0(xB.z + gam * o[6]); rB.w = fin0(xB.w + gam * o[7]);
        *(float4*)outb = rA;
        *(float4*)(outb + 4) = rB;
    }
}

extern "C" void kernel_launch(void* const* d_in, const int* in_sizes, int n_in,
                              void* d_out, int out_size, void* d_ws, size_t ws_size,
                              hipStream_t stream) {
    (void)d_ws; (void)ws_size;
    bool ok = (n_in == 8) &&
              in_sizes[0] == 4 * CHW &&
              in_sizes[1] == C_DIM * C_DIM && in_sizes[2] == C_DIM &&
              in_sizes[3] == C_DIM * C_DIM && in_sizes[4] == C_DIM &&
              in_sizes[5] == C_DIM * C_DIM && in_sizes[6] == C_DIM &&
              in_sizes[7] == 1 && out_size == 4 * CHW;
    if (!ok) {
        hipLaunchKernelGGL(k_sentinel, dim3((out_size + 255) / 256), dim3(256), 0, stream,
                           (ushort_t*)d_out, out_size);
        return;
    }
    hipLaunchKernelGGL(k_transpose, dim3(64, 4, 4), dim3(256), 0, stream, d_in[0]);
    hipLaunchKernelGGL(k_proj, dim3(32, 6, 4), dim3(256), 0, stream,
                       d_in[1], d_in[2], d_in[3], d_in[4], d_in[5], d_in[6]);
    hipLaunchKernelGGL(k_attn, dim3(1024), dim3(256), 0, stream);
    hipLaunchKernelGGL(k_combine, dim3(CHW / 2048, 4), dim3(256), 0, stream,
                       d_in[0], d_in[7], d_out);
}

// Round 13
// 219.881 us; speedup vs baseline: 2.1002x; 1.3126x over previous
//
#include <hip/hip_runtime.h>

typedef unsigned short ushort_t;
typedef unsigned int u32;
typedef _Float16 f16;
typedef f16 f16x8 __attribute__((ext_vector_type(8)));
typedef f16 f16x2 __attribute__((ext_vector_type(2)));
typedef ushort_t u16x8 __attribute__((ext_vector_type(8)));
typedef float f32x4 __attribute__((ext_vector_type(4)));
typedef float f32x16 __attribute__((ext_vector_type(16)));

#define C_DIM 256
#define HW 4096
#define CHW (C_DIM*HW)
#define L2E 1.4426950408889634f

// Device-global scratch. Internal pipeline f16.
__device__ __align__(16) f16 g_xbT[4 * CHW];
__device__ __align__(16) f16 g_q[4 * CHW];
__device__ __align__(16) f16 g_k[4 * CHW];
__device__ __align__(16) f16 g_v[4 * CHW];
__device__ __align__(16) f16 g_opart[16 * CHW];   // [slot=jq*4+n][c][i] normalized O^T
__device__ __align__(16) float g_ml[16 * 2 * HW]; // [slot][{m,l}][i]
__device__ __align__(16) f16 g_wf[3 * 65536];     // preconverted weights (f16)
__device__ __align__(16) float g_bf[3 * 256];     // preconverted biases (f32)

__device__ __forceinline__ float bf2f(ushort_t h) {
    union { u32 u; float f; } v; v.u = ((u32)h) << 16; return v.f;
}
__device__ __forceinline__ ushort_t f2bf(float f) {
    union { float f; u32 u; } v; v.f = f;
    u32 r = v.u + 0x7FFF + ((v.u >> 16) & 1);
    return (ushort_t)(r >> 16);
}
__device__ __forceinline__ float fin0(float v) {
    return (v > -1e30f && v < 1e30f) ? v : 0.f;
}
__device__ __forceinline__ f16 sf16(float v) {
    return (f16)((v > -1e4f && v < 1e4f) ? v : 0.f);
}
__device__ __forceinline__ void gl2lds16(const f16* g, f16* l) {
    __builtin_amdgcn_global_load_lds(
        (const __attribute__((address_space(1))) u32*)g,
        (__attribute__((address_space(3))) u32*)l, 16, 0, 0);
}
// Local dtype probe: read 64 halves as bf16; f32-misread low-halves decode huge.
__device__ __forceinline__ int probe_mode(const void* p) {
    int lane = threadIdx.x & 63;
    float v = fabsf(bf2f(((const ushort_t*)p)[lane]));
    v = (v < 1e6f) ? v : 1e6f;
#pragma unroll
    for (int d = 1; d < 64; d <<= 1) v += __shfl_xor(v, d, 64);
    return (v * (1.f / 64.f) > 100.f) ? 1 : 0;
}

__global__ void k_sentinel(ushort_t* out, int n) {
    int i = blockIdx.x * 256 + threadIdx.x;
    if (i < n) out[i] = f2bf(777.f);
}

// ---------------- kernel 0: preconvert weights/biases to f16/f32 -------------
__global__ __launch_bounds__(256) void k_wprep(
    const void* __restrict__ W0, const void* __restrict__ b0,
    const void* __restrict__ W1, const void* __restrict__ b1,
    const void* __restrict__ W2, const void* __restrict__ b2)
{
    int mat = blockIdx.y;
    const void* W = (mat == 0) ? W0 : (mat == 1) ? W1 : W2;
    const void* B = (mat == 0) ? b0 : (mat == 1) ? b1 : b2;
    int mode = probe_mode(W);
    int off = blockIdx.x * 2048 + threadIdx.x * 8;
    f16* dst = g_wf + mat * 65536 + off;
    f16x8 o;
    if (mode == 0) {
        u16x8 v = *(const u16x8*)((const ushort_t*)W + off);
#pragma unroll
        for (int e = 0; e < 8; ++e) o[e] = sf16(bf2f(v[e]));
    } else {
        const float* wf = (const float*)W + off;
        float4 a = *(const float4*)wf;
        float4 b = *(const float4*)(wf + 4);
        o[0]=sf16(a.x); o[1]=sf16(a.y); o[2]=sf16(a.z); o[3]=sf16(a.w);
        o[4]=sf16(b.x); o[5]=sf16(b.y); o[6]=sf16(b.z); o[7]=sf16(b.w);
    }
    *(f16x8*)dst = o;
    if (blockIdx.x == 0 && threadIdx.x < 32) {
#pragma unroll
        for (int e = 0; e < 8; ++e) {
            int i = threadIdx.x * 8 + e;
            g_bf[mat * 256 + i] = mode ? ((const float*)B)[i]
                                       : bf2f(((const ushort_t*)B)[i]);
        }
    }
}

// ---------------- kernel 1: x (N,C,HW) -> g_xbT f16 (N,HW,C) ----------------
__global__ __launch_bounds__(256) void k_transpose(const void* __restrict__ xv) {
    __shared__ f16 t[64][66];
    int mode = probe_mode(xv);
    int n = blockIdx.z, c0 = blockIdx.y * 64, l0 = blockIdx.x * 64;
    int tid = threadIdx.x;
    f16* ob = g_xbT + n * CHW;
    int lq = (tid & 15) * 4;
    int cl = tid >> 4;
    if (mode == 0) {
        const ushort_t* xb = (const ushort_t*)xv + n * CHW;
#pragma unroll
        for (int p = 0; p < 4; ++p) {
            int c = cl + 16 * p;
            ushort4 v = *(const ushort4*)(xb + (c0 + c) * HW + l0 + lq);
            t[lq + 0][c] = sf16(bf2f(v.x));
            t[lq + 1][c] = sf16(bf2f(v.y));
            t[lq + 2][c] = sf16(bf2f(v.z));
            t[lq + 3][c] = sf16(bf2f(v.w));
        }
    } else {
        const float* xb = (const float*)xv + n * CHW;
#pragma unroll
        for (int p = 0; p < 4; ++p) {
            int c = cl + 16 * p;
            float4 v = *(const float4*)(xb + (c0 + c) * HW + l0 + lq);
            t[lq + 0][c] = sf16(v.x);
            t[lq + 1][c] = sf16(v.y);
            t[lq + 2][c] = sf16(v.z);
            t[lq + 3][c] = sf16(v.w);
        }
    }
    __syncthreads();
    int c2 = (tid & 31) * 2;
    int lr = tid >> 5;
#pragma unroll
    for (int p = 0; p < 8; ++p) {
        int l = lr + 8 * p;
        u32 pair = *(const u32*)&t[l][c2];
        *(u32*)(ob + (l0 + l) * C_DIM + c0 + c2) = pair;
    }
}

// ---------------- kernel 2: projections (f16 MFMA, DMA-staged) ----------------
// Weights preconverted (k_wprep) -> no VALU conversion, no probe; both operand
// tiles staged via global_load_lds w=16 with pre-swizzled per-lane SOURCE
// (m173) reproducing the existing XOR layout; MFMA loop + epilogue unchanged.
// Barriers 12 -> 8 (2 per K-step). LDS 32KB -> ~5 blocks/CU.
__global__ __launch_bounds__(256) void k_proj() {
    __shared__ __align__(16) f16 lds_x[128 * 64];
    __shared__ __align__(16) f16 lds_w[128 * 64];
    int l0 = blockIdx.x * 128;
    int og0 = blockIdx.y * 128;
    int n = blockIdx.z;
    int mat = og0 >> 8;       // 0=q,1=k,2=v
    int om0 = og0 & 255;
    const f16* Wf = g_wf + mat * 65536;
    const float* Bf = g_bf + mat * 256;
    int tid = threadIdx.x, w = tid >> 6, lane = tid & 63;
    int quad = lane >> 4, l16 = lane & 15;
    const f16* xb = g_xbT + n * CHW;

    f32x4 acc[2][8];
#pragma unroll
    for (int a = 0; a < 2; a++)
#pragma unroll
        for (int b = 0; b < 8; b++) acc[a][b] = f32x4{0.f, 0.f, 0.f, 0.f};

    for (int ch = 0; ch < 4; ++ch) {
        int cc0 = ch * 64;
        // DMA stage: LDS granule g holds src row g>>3, col-granule (g&7)^(row&7)
#pragma unroll
        for (int s = 0; s < 4; ++s) {
            int g = s * 256 + tid;
            int row = g >> 3, gp = (g & 7) ^ (row & 7);
            gl2lds16(xb + (l0 + row) * C_DIM + cc0 + gp * 8,
                     lds_x + (s * 256 + w * 64) * 8);
            gl2lds16(Wf + (om0 + row) * C_DIM + cc0 + gp * 8,
                     lds_w + (s * 256 + w * 64) * 8);
        }
        asm volatile("s_waitcnt vmcnt(0)" ::: "memory");
        __builtin_amdgcn_s_barrier();
        __builtin_amdgcn_sched_barrier(0);
#pragma unroll
        for (int ks = 0; ks < 2; ++ks) {
            f16x8 af[2];
#pragma unroll
            for (int mt = 0; mt < 2; ++mt) {
                int row = w * 32 + mt * 16 + l16;
                int g = ks * 4 + quad;
                int pos = g ^ (row & 7);
                af[mt] = *(const f16x8*)(lds_x + (row * 8 + pos) * 8);
            }
#pragma unroll
            for (int nt = 0; nt < 8; ++nt) {
                int rowo = nt * 16 + l16;
                int g = ks * 4 + quad;
                int pos = g ^ (rowo & 7);
                f16x8 bfv = *(const f16x8*)(lds_w + (rowo * 8 + pos) * 8);
                if (mat < 2) {
                    acc[0][nt] = __builtin_amdgcn_mfma_f32_16x16x32_f16(af[0], bfv, acc[0][nt], 0, 0, 0);
                    acc[1][nt] = __builtin_amdgcn_mfma_f32_16x16x32_f16(af[1], bfv, acc[1][nt], 0, 0, 0);
                } else {
                    acc[0][nt] = __builtin_amdgcn_mfma_f32_16x16x32_f16(bfv, af[0], acc[0][nt], 0, 0, 0);
                    acc[1][nt] = __builtin_amdgcn_mfma_f32_16x16x32_f16(bfv, af[1], acc[1][nt], 0, 0, 0);
                }
            }
        }
        __builtin_amdgcn_s_barrier();   // LDS reads done -> next DMA safe
    }

    if (mat < 2) {
        f16* T = ((mat == 0) ? g_q : g_k) + n * CHW;
        float bvv[8];
#pragma unroll
        for (int nt = 0; nt < 8; nt++) bvv[nt] = Bf[om0 + nt * 16 + l16];
#pragma unroll
        for (int mt = 0; mt < 2; mt++)
#pragma unroll
            for (int nt = 0; nt < 8; nt++)
#pragma unroll
                for (int r = 0; r < 4; r++) {
                    int l = l0 + w * 32 + mt * 16 + quad * 4 + r;
                    int o = om0 + nt * 16 + l16;
                    T[l * C_DIM + o] = sf16(acc[mt][nt][r] + bvv[nt]);
                }
    } else {
        f16* T = g_v + n * CHW;
#pragma unroll
        for (int mt = 0; mt < 2; mt++)
#pragma unroll
            for (int nt = 0; nt < 8; nt++)
#pragma unroll
                for (int r = 0; r < 4; r++) {
                    int o = om0 + nt * 16 + quad * 4 + r;
                    int l = l0 + w * 32 + mt * 16 + l16;
                    T[o * HW + l] = sf16(acc[mt][nt][r] + Bf[o]);
                }
    }
}

// ---------------- kernel 3: flash attention, split-drain counted-vmcnt -------
// Reverted verbatim to the R9-measured version (101 us).
__device__ __forceinline__ f16x8 pack_pfrag(const float* p, int h) {
    union PK { u32 u; f16x2 h2; } t0, t1, t2, t3;
    t0.h2 = f16x2{(f16)p[0], (f16)p[1]};
    t1.h2 = f16x2{(f16)p[2], (f16)p[3]};
    t2.h2 = f16x2{(f16)p[4], (f16)p[5]};
    t3.h2 = f16x2{(f16)p[6], (f16)p[7]};
    u32 sa = __shfl_xor(t0.u, 32, 64);
    u32 sb = __shfl_xor(t1.u, 32, 64);
    u32 sc = __shfl_xor(t2.u, 32, 64);
    u32 sd = __shfl_xor(t3.u, 32, 64);
    union RW { u32 w[4]; f16x8 v; } r;
    r.w[0] = h ? sc : t0.u;
    r.w[1] = h ? sd : t1.u;
    r.w[2] = h ? t2.u : sa;
    r.w[3] = h ? t3.u : sb;
    return r.v;
}

__global__ __launch_bounds__(256, 2) void k_attn() {
    __shared__ __align__(16) f16 smem[32768];   // 64 KB
    f16* kbuf = smem;            // 2 slots x 8192 halves
    f16* vbuf = smem + 16384;    // 2 slots x 8192 halves

    int bid = blockIdx.x;
    int x8 = bid & 7;
    int n = x8 >> 1, jhi = x8 & 1;
    int rest = bid >> 3;
    int jlo = rest & 1;
    int i0 = (rest >> 1) * 128;
    int jq = jhi * 2 + jlo;
    int tid = threadIdx.x, w = tid >> 6, lane = tid & 63;
    int j5 = lane & 31, h = lane >> 5;

    const f16* Qb = g_q + n * CHW;
    const f16* Kb = g_k + n * CHW;
    const f16* Vb = g_v + n * CHW;

    f16x8 qf[16];
    {
        const f16* qrow = Qb + (i0 + w * 32 + j5) * C_DIM + h * 8;
#pragma unroll
        for (int ck = 0; ck < 16; ++ck)
            qf[ck] = *(const f16x8*)(qrow + ck * 16);
    }

    int k_lane = h * 256 + j5 * 8;
    int v_lane = h * 2048 + j5 * 8;

    const f16* ksrc = Kb + (jq * 1024 + j5) * C_DIM + (w * 2 + h) * 8;
    const f16* vsrc = Vb + tid * HW + jq * 1024;
    int dst_w = w * 512;

    f32x16 o_acc[8];
#pragma unroll
    for (int ct = 0; ct < 8; ++ct)
#pragma unroll
        for (int r = 0; r < 16; ++r) o_acc[ct][r] = 0.f;

    float m_ = -1e30f, l_ = 0.f, al_prev = 1.f;
    f16x8 pf0 = {}, pf1 = {};

    // prologue: stage K(0) -> kslot0; full drain; publish
#pragma unroll
    for (int s = 0; s < 4; ++s) gl2lds16(ksrc + s * 64, kbuf + s * 2048 + dst_w);
    ksrc += 32 * C_DIM;
    asm volatile("s_waitcnt vmcnt(0)" ::: "memory");
    __builtin_amdgcn_s_barrier();
    __builtin_amdgcn_sched_barrier(0);

    for (int it = 0; it < 31; ++it) {
        int kcur = it & 1;
        // issue K(it+1) [4 DMAs] THEN V(it) [4 DMAs] -- order pinned for vmcnt counts
#pragma unroll
        for (int s = 0; s < 4; ++s)
            gl2lds16(ksrc + s * 64, kbuf + (kcur ^ 1) * 8192 + s * 2048 + dst_w);
        ksrc += 32 * C_DIM;
        __builtin_amdgcn_sched_barrier(0);
#pragma unroll
        for (int s = 0; s < 4; ++s)
            gl2lds16(vsrc + s * 8, vbuf + kcur * 8192 + s * 2048 + dst_w);
        vsrc += 32;
        __builtin_amdgcn_sched_barrier(0);

        // ---- Phase A: S^T(it) = K Q^T (2 alternating acc chains) ----
        const f16* kb = kbuf + kcur * 8192 + k_lane;
        f32x16 sa, sb;
#pragma unroll
        for (int r = 0; r < 16; ++r) { sa[r] = 0.f; sb[r] = 0.f; }
        __builtin_amdgcn_s_setprio(1);
#pragma unroll
        for (int ck = 0; ck < 16; ++ck) {
            f16x8 kf = *(const f16x8*)(kb + ck * 512);
            if (ck & 1) sb = __builtin_amdgcn_mfma_f32_32x32x16_f16(kf, qf[ck], sb, 0, 0, 0);
            else        sa = __builtin_amdgcn_mfma_f32_32x32x16_f16(kf, qf[ck], sa, 0, 0, 0);
        }
        __builtin_amdgcn_s_setprio(0);
        f32x16 st;
#pragma unroll
        for (int r = 0; r < 16; ++r) st[r] = sa[r] + sb[r];

        // mid-iter: drain V(it-1) (4 oldest of 12); this iter's 8 stay in flight
        asm volatile("s_waitcnt vmcnt(8)" ::: "memory");
        __builtin_amdgcn_s_barrier();
        __builtin_amdgcn_sched_barrier(0);

        // ---- Phase B: rescale + PV(it-1) from vbuf[(it-1)&1]; softmax(it); pack ----
        if (it > 0) {
            if (__any(al_prev < 1.f)) {
#pragma unroll
                for (int ct = 0; ct < 8; ++ct)
#pragma unroll
                    for (int r = 0; r < 16; ++r) o_acc[ct][r] *= al_prev;
            }
            const f16* vb = vbuf + (kcur ^ 1) * 8192 + v_lane;
            __builtin_amdgcn_s_setprio(1);
#pragma unroll
            for (int ct = 0; ct < 8; ++ct) {
                f16x8 v0 = *(const f16x8*)(vb + ct * 256);
                f16x8 v1 = *(const f16x8*)(vb + 4096 + ct * 256);
                o_acc[ct] = __builtin_amdgcn_mfma_f32_32x32x16_f16(v0, pf0, o_acc[ct], 0, 0, 0);
                o_acc[ct] = __builtin_amdgcn_mfma_f32_32x32x16_f16(v1, pf1, o_acc[ct], 0, 0, 0);
            }
            __builtin_amdgcn_s_setprio(0);
        }

        // online softmax over j (rows of S^T), per i = lane&31
        float mx0 = fmaxf(fmaxf(st[0], st[1]), fmaxf(st[2], st[3]));
        float mx1 = fmaxf(fmaxf(st[4], st[5]), fmaxf(st[6], st[7]));
        float mx2 = fmaxf(fmaxf(st[8], st[9]), fmaxf(st[10], st[11]));
        float mx3 = fmaxf(fmaxf(st[12], st[13]), fmaxf(st[14], st[15]));
        float smax = fmaxf(fmaxf(mx0, mx1), fmaxf(mx2, mx3));
        smax = fmaxf(smax, __shfl_xor(smax, 32, 64));
        float mq = __builtin_ceilf(smax * 0.125f) * 8.f;   // quantized max
        float mn = fmaxf(m_, mq);
        float al = __builtin_amdgcn_exp2f((m_ - mn) * L2E);
        float nl = -mn * L2E;
        float p[16];
#pragma unroll
        for (int r = 0; r < 16; ++r)
            p[r] = __builtin_amdgcn_exp2f(st[r] * L2E + nl);
        float a0 = (p[0] + p[1]) + (p[2] + p[3]);
        float a1 = (p[4] + p[5]) + (p[6] + p[7]);
        float a2 = (p[8] + p[9]) + (p[10] + p[11]);
        float a3 = (p[12] + p[13]) + (p[14] + p[15]);
        float rs = (a0 + a1) + (a2 + a3);   // per-half partial; cross-add deferred
        m_ = mn;
        l_ = l_ * al + rs;
        al_prev = al;
        pf0 = pack_pfrag(p, h);
        pf1 = pack_pfrag(p + 8, h);

        // end-iter: drain K(it+1) (4 oldest of 8); V(it) stays in flight
        asm volatile("s_waitcnt vmcnt(4)" ::: "memory");
        __builtin_amdgcn_s_barrier();
        __builtin_amdgcn_sched_barrier(0);
    }

    // ---- peeled it=31 (kcur=1): no K issue; V(31) -> vbuf[1] ----
    {
#pragma unroll
        for (int s = 0; s < 4; ++s)
            gl2lds16(vsrc + s * 8, vbuf + 8192 + s * 2048 + dst_w);
        __builtin_amdgcn_sched_barrier(0);

        // Phase A: S^T(31) from kbuf[1]
        const f16* kb = kbuf + 8192 + k_lane;
        f32x16 sa, sb;
#pragma unroll
        for (int r = 0; r < 16; ++r) { sa[r] = 0.f; sb[r] = 0.f; }
        __builtin_amdgcn_s_setprio(1);
#pragma unroll
        for (int ck = 0; ck < 16; ++ck) {
            f16x8 kf = *(const f16x8*)(kb + ck * 512);
            if (ck & 1) sb = __builtin_amdgcn_mfma_f32_32x32x16_f16(kf, qf[ck], sb, 0, 0, 0);
            else        sa = __builtin_amdgcn_mfma_f32_32x32x16_f16(kf, qf[ck], sa, 0, 0, 0);
        }
        __builtin_amdgcn_s_setprio(0);
        f32x16 st;
#pragma unroll
        for (int r = 0; r < 16; ++r) st[r] = sa[r] + sb[r];

        // drain V(30) (4 oldest of 8); V(31) stays
        asm volatile("s_waitcnt vmcnt(4)" ::: "memory");
        __builtin_amdgcn_s_barrier();
        __builtin_amdgcn_sched_barrier(0);

        // Phase B: rescale + PV(30) from vbuf[0] (old pf), then softmax(31)+pack
        if (__any(al_prev < 1.f)) {
#pragma unroll
            for (int ct = 0; ct < 8; ++ct)
#pragma unroll
                for (int r = 0; r < 16; ++r) o_acc[ct][r] *= al_prev;
        }
        {
            const f16* vb = vbuf + v_lane;
            __builtin_amdgcn_s_setprio(1);
#pragma unroll
            for (int ct = 0; ct < 8; ++ct) {
                f16x8 v0 = *(const f16x8*)(vb + ct * 256);
                f16x8 v1 = *(const f16x8*)(vb + 4096 + ct * 256);
                o_acc[ct] = __builtin_amdgcn_mfma_f32_32x32x16_f16(v0, pf0, o_acc[ct], 0, 0, 0);
                o_acc[ct] = __builtin_amdgcn_mfma_f32_32x32x16_f16(v1, pf1, o_acc[ct], 0, 0, 0);
            }
            __builtin_amdgcn_s_setprio(0);
        }
        float mx0 = fmaxf(fmaxf(st[0], st[1]), fmaxf(st[2], st[3]));
        float mx1 = fmaxf(fmaxf(st[4], st[5]), fmaxf(st[6], st[7]));
        float mx2 = fmaxf(fmaxf(st[8], st[9]), fmaxf(st[10], st[11]));
        float mx3 = fmaxf(fmaxf(st[12], st[13]), fmaxf(st[14], st[15]));
        float smax = fmaxf(fmaxf(mx0, mx1), fmaxf(mx2, mx3));
        smax = fmaxf(smax, __shfl_xor(smax, 32, 64));
        float mq = __builtin_ceilf(smax * 0.125f) * 8.f;
        float mn = fmaxf(m_, mq);
        float al = __builtin_amdgcn_exp2f((m_ - mn) * L2E);
        float nl = -mn * L2E;
        float p[16];
#pragma unroll
        for (int r = 0; r < 16; ++r)
            p[r] = __builtin_amdgcn_exp2f(st[r] * L2E + nl);
        float a0 = (p[0] + p[1]) + (p[2] + p[3]);
        float a1 = (p[4] + p[5]) + (p[6] + p[7]);
        float a2 = (p[8] + p[9]) + (p[10] + p[11]);
        float a3 = (p[12] + p[13]) + (p[14] + p[15]);
        float rs = (a0 + a1) + (a2 + a3);
        m_ = mn;
        l_ = l_ * al + rs;
        al_prev = al;
        pf0 = pack_pfrag(p, h);
        pf1 = pack_pfrag(p + 8, h);

        // drain V(31); publish
        asm volatile("s_waitcnt vmcnt(0)" ::: "memory");
        __builtin_amdgcn_s_barrier();
        __builtin_amdgcn_sched_barrier(0);

        // final PV(31) from vbuf[1]
        if (__any(al_prev < 1.f)) {
#pragma unroll
            for (int ct = 0; ct < 8; ++ct)
#pragma unroll
                for (int r = 0; r < 16; ++r) o_acc[ct][r] *= al_prev;
        }
        const f16* vb = vbuf + 8192 + v_lane;
#pragma unroll
        for (int ct = 0; ct < 8; ++ct) {
            f16x8 v0 = *(const f16x8*)(vb + ct * 256);
            f16x8 v1 = *(const f16x8*)(vb + 4096 + ct * 256);
            o_acc[ct] = __builtin_amdgcn_mfma_f32_32x32x16_f16(v0, pf0, o_acc[ct], 0, 0, 0);
            o_acc[ct] = __builtin_amdgcn_mfma_f32_32x32x16_f16(v1, pf1, o_acc[ct], 0, 0, 0);
        }
    }

    // ---- epilogue: complete the deferred cross-half l reduction ----
    l_ += __shfl_xor(l_, 32, 64);

    // ---- write partials ----
    int slot = jq * 4 + n;
    int i_out = i0 + w * 32 + j5;
    if (h == 0) {
        g_ml[(slot * 2 + 0) * HW + i_out] = m_;
        g_ml[(slot * 2 + 1) * HW + i_out] = l_;
    }
    float inv = (l_ > 1e-30f) ? 1.f / l_ : 0.f;
    f16* ob = g_opart + slot * CHW + i_out;
#pragma unroll
    for (int ct = 0; ct < 8; ++ct) {
        int cbase = ct * 32 + 4 * h;
#pragma unroll
        for (int r = 0; r < 16; ++r) {
            int c = cbase + (r & 3) + 8 * (r >> 2);
            ob[c * HW] = (f16)(o_acc[ct][r] * inv);
        }
    }
}

// ---------------- kernel 4: merge 4 j-quarters + residual + store (8-wide) ----------------
__global__ __launch_bounds__(256) void k_combine(
    const void* __restrict__ xv, const void* __restrict__ gv, void* __restrict__ outv)
{
    int mode = probe_mode(xv);
    float gam = fin0(mode ? ((const float*)gv)[0] : bf2f(((const ushort_t*)gv)[0]));
    int n = blockIdx.y;
    int off = blockIdx.x * 2048 + threadIdx.x * 8;   // 8 consecutive i, same c
    int i = off & (HW - 1);

    u16x8 op[4];
    float ms[4][8], ls[4][8];
#pragma unroll
    for (int s = 0; s < 4; ++s) {
        int slot = s * 4 + n;
        op[s] = *(const u16x8*)((const ushort_t*)g_opart + slot * CHW + off);
        float4 mA = *(const float4*)&g_ml[(slot * 2 + 0) * HW + i];
        float4 mB = *(const float4*)&g_ml[(slot * 2 + 0) * HW + i + 4];
        float4 lA = *(const float4*)&g_ml[(slot * 2 + 1) * HW + i];
        float4 lB = *(const float4*)&g_ml[(slot * 2 + 1) * HW + i + 4];
        ms[s][0]=mA.x; ms[s][1]=mA.y; ms[s][2]=mA.z; ms[s][3]=mA.w;
        ms[s][4]=mB.x; ms[s][5]=mB.y; ms[s][6]=mB.z; ms[s][7]=mB.w;
        ls[s][0]=lA.x; ls[s][1]=lA.y; ls[s][2]=lA.z; ls[s][3]=lA.w;
        ls[s][4]=lB.x; ls[s][5]=lB.y; ls[s][6]=lB.z; ls[s][7]=lB.w;
    }

    float o[8];
#pragma unroll
    for (int e = 0; e < 8; ++e) {
        float m = fmaxf(fmaxf(ms[0][e], ms[1][e]), fmaxf(ms[2][e], ms[3][e]));
        float num = 0.f, den = 0.f;
#pragma unroll
        for (int s = 0; s < 4; ++s) {
            float wgt = __builtin_amdgcn_exp2f((ms[s][e] - m) * L2E) * ls[s][e];
            union { ushort_t u; f16 h; } cv; cv.u = (ushort_t)op[s][e];
            num += wgt * (float)cv.h;
            den += wgt;
        }
        o[e] = (den > 1e-30f) ? num / den : 0.f;
    }

    if (mode == 0) {
        u16x8 xp = *(const u16x8*)((const ushort_t*)xv + n * CHW + off);
        u16x8 res;
#pragma unroll
        for (int e = 0; e < 8; ++e)
            res[e] = f2bf(fin0(bf2f((ushort_t)xp[e]) + gam * o[e]));
        *(u16x8*)((ushort_t*)outv + n * CHW + off) = res;
    } else {
        const float* xb = (const float*)xv + n * CHW + off;
        float* outb = (float*)outv + n * CHW + off;
        float4 xA = *(const float4*)xb;
        float4 xB = *(const float4*)(xb + 4);
        float4 rA, rB;
        rA.x = fin0(xA.x + gam * o[0]); rA.y = fin0(xA.y + gam * o[1]);
        rA.z = fin0(xA.z + gam * o[2]); rA.w = fin0(xA.w + gam * o[3]);
        rB.x = fin0(xB.x + gam * o[4]); rB.y = fin0(xB.y + gam * o[5]);
        rB.z = fin0(xB.z + gam * o[6]); rB.w = fin0(xB.w + gam * o[7]);
        *(float4*)outb = rA;
        *(float4*)(outb + 4) = rB;
    }
}

extern "C" void kernel_launch(void* const* d_in, const int* in_sizes, int n_in,
                              void* d_out, int out_size, void* d_ws, size_t ws_size,
                              hipStream_t stream) {
    (void)d_ws; (void)ws_size;
    bool ok = (n_in == 8) &&
              in_sizes[0] == 4 * CHW &&
              in_sizes[1] == C_DIM * C_DIM && in_sizes[2] == C_DIM &&
              in_sizes[3] == C_DIM * C_DIM && in_sizes[4] == C_DIM &&
              in_sizes[5] == C_DIM * C_DIM && in_sizes[6] == C_DIM &&
              in_sizes[7] == 1 && out_size == 4 * CHW;
    if (!ok) {
        hipLaunchKernelGGL(k_sentinel, dim3((out_size + 255) / 256), dim3(256), 0, stream,
                           (ushort_t*)d_out, out_size);
        return;
    }
    hipLaunchKernelGGL(k_wprep, dim3(32, 3), dim3(256), 0, stream,
                       d_in[1], d_in[2], d_in[3], d_in[4], d_in[5], d_in[6]);
    hipLaunchKernelGGL(k_transpose, dim3(64, 4, 4), dim3(256), 0, stream, d_in[0]);
    hipLaunchKernelGGL(k_proj, dim3(32, 6, 4), dim3(256), 0, stream);
    hipLaunchKernelGGL(k_attn, dim3(512), dim3(256), 0, stream);
    hipLaunchKernelGGL(k_combine, dim3(CHW / 2048, 4), dim3(256), 0, stream,
                       d_in[0], d_in[7], d_out);
}

// Round 15
// 212.746 us; speedup vs baseline: 2.1706x; 1.0335x over previous
//
#include <hip/hip_runtime.h>

typedef unsigned short ushort_t;
typedef unsigned int u32;
typedef _Float16 f16;
typedef f16 f16x8 __attribute__((ext_vector_type(8)));
typedef f16 f16x2 __attribute__((ext_vector_type(2)));
typedef ushort_t u16x8 __attribute__((ext_vector_type(8)));
typedef float f32x4 __attribute__((ext_vector_type(4)));
typedef float f32x16 __attribute__((ext_vector_type(16)));

#define C_DIM 256
#define HW 4096
#define CHW (C_DIM*HW)
#define L2E 1.4426950408889634f

// Device-global scratch. Internal pipeline f16.
__device__ __align__(16) f16 g_xbT[4 * CHW];
__device__ __align__(16) f16 g_q[4 * CHW];
__device__ __align__(16) f16 g_k[4 * CHW];
__device__ __align__(16) f16 g_v[4 * CHW];
__device__ __align__(16) f16 g_opart[16 * CHW];   // [slot=jq*4+n][c][i] normalized O^T
__device__ __align__(16) float g_ml[16 * 2 * HW]; // [slot][{m,l}][i]
__device__ __align__(16) f16 g_wf[3 * 65536];     // preconverted weights (f16)
__device__ __align__(16) float g_bf[3 * 256];     // preconverted biases (f32)

__device__ __forceinline__ float bf2f(ushort_t h) {
    union { u32 u; float f; } v; v.u = ((u32)h) << 16; return v.f;
}
__device__ __forceinline__ ushort_t f2bf(float f) {
    union { float f; u32 u; } v; v.f = f;
    u32 r = v.u + 0x7FFF + ((v.u >> 16) & 1);
    return (ushort_t)(r >> 16);
}
__device__ __forceinline__ float fin0(float v) {
    return (v > -1e30f && v < 1e30f) ? v : 0.f;
}
__device__ __forceinline__ f16 sf16(float v) {
    return (f16)((v > -1e4f && v < 1e4f) ? v : 0.f);
}
__device__ __forceinline__ void gl2lds16(const f16* g, f16* l) {
    __builtin_amdgcn_global_load_lds(
        (const __attribute__((address_space(1))) u32*)g,
        (__attribute__((address_space(3))) u32*)l, 16, 0, 0);
}
// Local dtype probe: read 64 halves as bf16; f32-misread low-halves decode huge.
__device__ __forceinline__ int probe_mode(const void* p) {
    int lane = threadIdx.x & 63;
    float v = fabsf(bf2f(((const ushort_t*)p)[lane]));
    v = (v < 1e6f) ? v : 1e6f;
#pragma unroll
    for (int d = 1; d < 64; d <<= 1) v += __shfl_xor(v, d, 64);
    return (v * (1.f / 64.f) > 100.f) ? 1 : 0;
}

__global__ void k_sentinel(ushort_t* out, int n) {
    int i = blockIdx.x * 256 + threadIdx.x;
    if (i < n) out[i] = f2bf(777.f);
}

// ---------------- kernel 1: transpose + wprep (merged single launch) --------
// z<4: x (N,C,HW) -> g_xbT f16 (N,HW,C).  z==4: preconvert W/b -> g_wf/g_bf.
__global__ __launch_bounds__(256) void k_prep(
    const void* __restrict__ xv,
    const void* __restrict__ W0, const void* __restrict__ b0,
    const void* __restrict__ W1, const void* __restrict__ b1,
    const void* __restrict__ W2, const void* __restrict__ b2)
{
    if (blockIdx.z == 4) {
        // ---- wprep path: needs blockIdx.x<32, blockIdx.y<3 ----
        int mat = blockIdx.y;
        if (mat >= 3 || blockIdx.x >= 32) return;
        const void* W = (mat == 0) ? W0 : (mat == 1) ? W1 : W2;
        const void* B = (mat == 0) ? b0 : (mat == 1) ? b1 : b2;
        int mode = probe_mode(W);
        int off = blockIdx.x * 2048 + threadIdx.x * 8;
        f16* dst = g_wf + mat * 65536 + off;
        f16x8 o;
        if (mode == 0) {
            u16x8 v = *(const u16x8*)((const ushort_t*)W + off);
#pragma unroll
            for (int e = 0; e < 8; ++e) o[e] = sf16(bf2f(v[e]));
        } else {
            const float* wf = (const float*)W + off;
            float4 a = *(const float4*)wf;
            float4 b = *(const float4*)(wf + 4);
            o[0]=sf16(a.x); o[1]=sf16(a.y); o[2]=sf16(a.z); o[3]=sf16(a.w);
            o[4]=sf16(b.x); o[5]=sf16(b.y); o[6]=sf16(b.z); o[7]=sf16(b.w);
        }
        *(f16x8*)dst = o;
        if (blockIdx.x == 0 && threadIdx.x < 32) {
#pragma unroll
            for (int e = 0; e < 8; ++e) {
                int i = threadIdx.x * 8 + e;
                g_bf[mat * 256 + i] = mode ? ((const float*)B)[i]
                                           : bf2f(((const ushort_t*)B)[i]);
            }
        }
        return;
    }
    // ---- transpose path ----
    __shared__ f16 t[64][66];
    int mode = probe_mode(xv);
    int n = blockIdx.z, c0 = blockIdx.y * 64, l0 = blockIdx.x * 64;
    int tid = threadIdx.x;
    f16* ob = g_xbT + n * CHW;
    int lq = (tid & 15) * 4;
    int cl = tid >> 4;
    if (mode == 0) {
        const ushort_t* xb = (const ushort_t*)xv + n * CHW;
#pragma unroll
        for (int p = 0; p < 4; ++p) {
            int c = cl + 16 * p;
            ushort4 v = *(const ushort4*)(xb + (c0 + c) * HW + l0 + lq);
            t[lq + 0][c] = sf16(bf2f(v.x));
            t[lq + 1][c] = sf16(bf2f(v.y));
            t[lq + 2][c] = sf16(bf2f(v.z));
            t[lq + 3][c] = sf16(bf2f(v.w));
        }
    } else {
        const float* xb = (const float*)xv + n * CHW;
#pragma unroll
        for (int p = 0; p < 4; ++p) {
            int c = cl + 16 * p;
            float4 v = *(const float4*)(xb + (c0 + c) * HW + l0 + lq);
            t[lq + 0][c] = sf16(v.x);
            t[lq + 1][c] = sf16(v.y);
            t[lq + 2][c] = sf16(v.z);
            t[lq + 3][c] = sf16(v.w);
        }
    }
    __syncthreads();
    int c2 = (tid & 31) * 2;
    int lr = tid >> 5;
#pragma unroll
    for (int p = 0; p < 8; ++p) {
        int l = lr + 8 * p;
        u32 pair = *(const u32*)&t[l][c2];
        *(u32*)(ob + (l0 + l) * C_DIM + c0 + c2) = pair;
    }
}

// ---------------- kernel 2: projections (f16 MFMA, DMA-staged) ----------------
// W double-buffered (2x16KB) + x single (16KB) = 48KB -> 3 blocks/CU.
// W(ch+1) DMA issued BEFORE ch's MFMA loop (targets idle buffer; overlaps with
// compute); x(ch+1) staged after the post-MFMA barrier. End-of-ch vmcnt(0)
// exposes only the x latency -- W half of the drain rides under MFMA.
__global__ __launch_bounds__(256) void k_proj() {
    __shared__ __align__(16) f16 lds_x[128 * 64];
    __shared__ __align__(16) f16 lds_w[2][128 * 64];
    int l0 = blockIdx.x * 128;
    int og0 = blockIdx.y * 128;
    int n = blockIdx.z;
    int mat = og0 >> 8;       // 0=q,1=k,2=v
    int om0 = og0 & 255;
    const f16* Wf = g_wf + mat * 65536;
    const float* Bf = g_bf + mat * 256;
    int tid = threadIdx.x, w = tid >> 6, lane = tid & 63;
    int quad = lane >> 4, l16 = lane & 15;
    const f16* xb = g_xbT + n * CHW;

    // per-thread DMA source descriptors (granule g = s*256+tid)
    int srow[4], sgp[4];
#pragma unroll
    for (int s = 0; s < 4; ++s) {
        int g = s * 256 + tid;
        srow[s] = g >> 3;
        sgp[s] = (g & 7) ^ (srow[s] & 7);
    }

    f32x4 acc[2][8];
#pragma unroll
    for (int a = 0; a < 2; a++)
#pragma unroll
        for (int b = 0; b < 8; b++) acc[a][b] = f32x4{0.f, 0.f, 0.f, 0.f};

    // prologue: stage x(0) + W(0)
#pragma unroll
    for (int s = 0; s < 4; ++s) {
        gl2lds16(xb + (l0 + srow[s]) * C_DIM + 0 + sgp[s] * 8,
                 lds_x + (s * 256 + w * 64) * 8);
        gl2lds16(Wf + (om0 + srow[s]) * C_DIM + 0 + sgp[s] * 8,
                 lds_w[0] + (s * 256 + w * 64) * 8);
    }
    asm volatile("s_waitcnt vmcnt(0)" ::: "memory");
    __builtin_amdgcn_s_barrier();
    __builtin_amdgcn_sched_barrier(0);

    for (int ch = 0; ch < 4; ++ch) {
        int cc0 = ch * 64;
        int cur = ch & 1;
        // issue W(ch+1) into the idle buffer; overlaps with this ch's MFMAs
        if (ch < 3) {
#pragma unroll
            for (int s = 0; s < 4; ++s)
                gl2lds16(Wf + (om0 + srow[s]) * C_DIM + (cc0 + 64) + sgp[s] * 8,
                         lds_w[cur ^ 1] + (s * 256 + w * 64) * 8);
        }
        __builtin_amdgcn_sched_barrier(0);
#pragma unroll
        for (int ks = 0; ks < 2; ++ks) {
            f16x8 af[2];
#pragma unroll
            for (int mt = 0; mt < 2; ++mt) {
                int row = w * 32 + mt * 16 + l16;
                int g = ks * 4 + quad;
                int pos = g ^ (row & 7);
                af[mt] = *(const f16x8*)(lds_x + (row * 8 + pos) * 8);
            }
#pragma unroll
            for (int nt = 0; nt < 8; ++nt) {
                int rowo = nt * 16 + l16;
                int g = ks * 4 + quad;
                int pos = g ^ (rowo & 7);
                f16x8 bfv = *(const f16x8*)(lds_w[cur] + (rowo * 8 + pos) * 8);
                if (mat < 2) {
                    acc[0][nt] = __builtin_amdgcn_mfma_f32_16x16x32_f16(af[0], bfv, acc[0][nt], 0, 0, 0);
                    acc[1][nt] = __builtin_amdgcn_mfma_f32_16x16x32_f16(af[1], bfv, acc[1][nt], 0, 0, 0);
                } else {
                    acc[0][nt] = __builtin_amdgcn_mfma_f32_16x16x32_f16(bfv, af[0], acc[0][nt], 0, 0, 0);
                    acc[1][nt] = __builtin_amdgcn_mfma_f32_16x16x32_f16(bfv, af[1], acc[1][nt], 0, 0, 0);
                }
            }
        }
        __builtin_amdgcn_s_barrier();   // lds_x / lds_w[cur] reads done
        __builtin_amdgcn_sched_barrier(0);
        if (ch < 3) {
            // stage x(ch+1) into the (now-free) single x buffer
#pragma unroll
            for (int s = 0; s < 4; ++s)
                gl2lds16(xb + (l0 + srow[s]) * C_DIM + (cc0 + 64) + sgp[s] * 8,
                         lds_x + (s * 256 + w * 64) * 8);
            // drain x(ch+1) AND W(ch+1) (issued pre-MFMA, likely landed)
            asm volatile("s_waitcnt vmcnt(0)" ::: "memory");
            __builtin_amdgcn_s_barrier();
            __builtin_amdgcn_sched_barrier(0);
        }
    }

    if (mat < 2) {
        f16* T = ((mat == 0) ? g_q : g_k) + n * CHW;
        float bvv[8];
#pragma unroll
        for (int nt = 0; nt < 8; nt++) bvv[nt] = Bf[om0 + nt * 16 + l16];
#pragma unroll
        for (int mt = 0; mt < 2; mt++)
#pragma unroll
            for (int nt = 0; nt < 8; nt++)
#pragma unroll
                for (int r = 0; r < 4; r++) {
                    int l = l0 + w * 32 + mt * 16 + quad * 4 + r;
                    int o = om0 + nt * 16 + l16;
                    T[l * C_DIM + o] = sf16(acc[mt][nt][r] + bvv[nt]);
                }
    } else {
        f16* T = g_v + n * CHW;
#pragma unroll
        for (int mt = 0; mt < 2; mt++)
#pragma unroll
            for (int nt = 0; nt < 8; nt++)
#pragma unroll
                for (int r = 0; r < 4; r++) {
                    int o = om0 + nt * 16 + quad * 4 + r;
                    int l = l0 + w * 32 + mt * 16 + l16;
                    T[o * HW + l] = sf16(acc[mt][nt][r] + Bf[o]);
                }
    }
}

// ---------------- kernel 3: flash attention, split-drain counted-vmcnt -------
// R9-measured version (101 us), unchanged.
__device__ __forceinline__ f16x8 pack_pfrag(const float* p, int h) {
    union PK { u32 u; f16x2 h2; } t0, t1, t2, t3;
    t0.h2 = f16x2{(f16)p[0], (f16)p[1]};
    t1.h2 = f16x2{(f16)p[2], (f16)p[3]};
    t2.h2 = f16x2{(f16)p[4], (f16)p[5]};
    t3.h2 = f16x2{(f16)p[6], (f16)p[7]};
    u32 sa = __shfl_xor(t0.u, 32, 64);
    u32 sb = __shfl_xor(t1.u, 32, 64);
    u32 sc = __shfl_xor(t2.u, 32, 64);
    u32 sd = __shfl_xor(t3.u, 32, 64);
    union RW { u32 w[4]; f16x8 v; } r;
    r.w[0] = h ? sc : t0.u;
    r.w[1] = h ? sd : t1.u;
    r.w[2] = h ? t2.u : sa;
    r.w[3] = h ? t3.u : sb;
    return r.v;
}

__global__ __launch_bounds__(256, 2) void k_attn() {
    __shared__ __align__(16) f16 smem[32768];   // 64 KB
    f16* kbuf = smem;            // 2 slots x 8192 halves
    f16* vbuf = smem + 16384;    // 2 slots x 8192 halves

    int bid = blockIdx.x;
    int x8 = bid & 7;
    int n = x8 >> 1, jhi = x8 & 1;
    int rest = bid >> 3;
    int jlo = rest & 1;
    int i0 = (rest >> 1) * 128;
    int jq = jhi * 2 + jlo;
    int tid = threadIdx.x, w = tid >> 6, lane = tid & 63;
    int j5 = lane & 31, h = lane >> 5;

    const f16* Qb = g_q + n * CHW;
    const f16* Kb = g_k + n * CHW;
    const f16* Vb = g_v + n * CHW;

    f16x8 qf[16];
    {
        const f16* qrow = Qb + (i0 + w * 32 + j5) * C_DIM + h * 8;
#pragma unroll
        for (int ck = 0; ck < 16; ++ck)
            qf[ck] = *(const f16x8*)(qrow + ck * 16);
    }

    int k_lane = h * 256 + j5 * 8;
    int v_lane = h * 2048 + j5 * 8;

    const f16* ksrc = Kb + (jq * 1024 + j5) * C_DIM + (w * 2 + h) * 8;
    const f16* vsrc = Vb + tid * HW + jq * 1024;
    int dst_w = w * 512;

    f32x16 o_acc[8];
#pragma unroll
    for (int ct = 0; ct < 8; ++ct)
#pragma unroll
        for (int r = 0; r < 16; ++r) o_acc[ct][r] = 0.f;

    float m_ = -1e30f, l_ = 0.f, al_prev = 1.f;
    f16x8 pf0 = {}, pf1 = {};

    // prologue: stage K(0) -> kslot0; full drain; publish
#pragma unroll
    for (int s = 0; s < 4; ++s) gl2lds16(ksrc + s * 64, kbuf + s * 2048 + dst_w);
    ksrc += 32 * C_DIM;
    asm volatile("s_waitcnt vmcnt(0)" ::: "memory");
    __builtin_amdgcn_s_barrier();
    __builtin_amdgcn_sched_barrier(0);

    for (int it = 0; it < 31; ++it) {
        int kcur = it & 1;
        // issue K(it+1) [4 DMAs] THEN V(it) [4 DMAs] -- order pinned for vmcnt counts
#pragma unroll
        for (int s = 0; s < 4; ++s)
            gl2lds16(ksrc + s * 64, kbuf + (kcur ^ 1) * 8192 + s * 2048 + dst_w);
        ksrc += 32 * C_DIM;
        __builtin_amdgcn_sched_barrier(0);
#pragma unroll
        for (int s = 0; s < 4; ++s)
            gl2lds16(vsrc + s * 8, vbuf + kcur * 8192 + s * 2048 + dst_w);
        vsrc += 32;
        __builtin_amdgcn_sched_barrier(0);

        // ---- Phase A: S^T(it) = K Q^T (2 alternating acc chains) ----
        const f16* kb = kbuf + kcur * 8192 + k_lane;
        f32x16 sa, sb;
#pragma unroll
        for (int r = 0; r < 16; ++r) { sa[r] = 0.f; sb[r] = 0.f; }
        __builtin_amdgcn_s_setprio(1);
#pragma unroll
        for (int ck = 0; ck < 16; ++ck) {
            f16x8 kf = *(const f16x8*)(kb + ck * 512);
            if (ck & 1) sb = __builtin_amdgcn_mfma_f32_32x32x16_f16(kf, qf[ck], sb, 0, 0, 0);
            else        sa = __builtin_amdgcn_mfma_f32_32x32x16_f16(kf, qf[ck], sa, 0, 0, 0);
        }
        __builtin_amdgcn_s_setprio(0);
        f32x16 st;
#pragma unroll
        for (int r = 0; r < 16; ++r) st[r] = sa[r] + sb[r];

        // mid-iter: drain V(it-1) (4 oldest of 12); this iter's 8 stay in flight
        asm volatile("s_waitcnt vmcnt(8)" ::: "memory");
        __builtin_amdgcn_s_barrier();
        __builtin_amdgcn_sched_barrier(0);

        // ---- Phase B: rescale + PV(it-1) from vbuf[(it-1)&1]; softmax(it); pack ----
        if (it > 0) {
            if (__any(al_prev < 1.f)) {
#pragma unroll
                for (int ct = 0; ct < 8; ++ct)
#pragma unroll
                    for (int r = 0; r < 16; ++r) o_acc[ct][r] *= al_prev;
            }
            const f16* vb = vbuf + (kcur ^ 1) * 8192 + v_lane;
            __builtin_amdgcn_s_setprio(1);
#pragma unroll
            for (int ct = 0; ct < 8; ++ct) {
                f16x8 v0 = *(const f16x8*)(vb + ct * 256);
                f16x8 v1 = *(const f16x8*)(vb + 4096 + ct * 256);
                o_acc[ct] = __builtin_amdgcn_mfma_f32_32x32x16_f16(v0, pf0, o_acc[ct], 0, 0, 0);
                o_acc[ct] = __builtin_amdgcn_mfma_f32_32x32x16_f16(v1, pf1, o_acc[ct], 0, 0, 0);
            }
            __builtin_amdgcn_s_setprio(0);
        }

        // online softmax over j (rows of S^T), per i = lane&31
        float mx0 = fmaxf(fmaxf(st[0], st[1]), fmaxf(st[2], st[3]));
        float mx1 = fmaxf(fmaxf(st[4], st[5]), fmaxf(st[6], st[7]));
        float mx2 = fmaxf(fmaxf(st[8], st[9]), fmaxf(st[10], st[11]));
        float mx3 = fmaxf(fmaxf(st[12], st[13]), fmaxf(st[14], st[15]));
        float smax = fmaxf(fmaxf(mx0, mx1), fmaxf(mx2, mx3));
        smax = fmaxf(smax, __shfl_xor(smax, 32, 64));
        float mq = __builtin_ceilf(smax * 0.125f) * 8.f;   // quantized max
        float mn = fmaxf(m_, mq);
        float al = __builtin_amdgcn_exp2f((m_ - mn) * L2E);
        float nl = -mn * L2E;
        float p[16];
#pragma unroll
        for (int r = 0; r < 16; ++r)
            p[r] = __builtin_amdgcn_exp2f(st[r] * L2E + nl);
        float a0 = (p[0] + p[1]) + (p[2] + p[3]);
        float a1 = (p[4] + p[5]) + (p[6] + p[7]);
        float a2 = (p[8] + p[9]) + (p[10] + p[11]);
        float a3 = (p[12] + p[13]) + (p[14] + p[15]);
        float rs = (a0 + a1) + (a2 + a3);   // per-half partial; cross-add deferred
        m_ = mn;
        l_ = l_ * al + rs;
        al_prev = al;
        pf0 = pack_pfrag(p, h);
        pf1 = pack_pfrag(p + 8, h);

        // end-iter: drain K(it+1) (4 oldest of 8); V(it) stays in flight
        asm volatile("s_waitcnt vmcnt(4)" ::: "memory");
        __builtin_amdgcn_s_barrier();
        __builtin_amdgcn_sched_barrier(0);
    }

    // ---- peeled it=31 (kcur=1): no K issue; V(31) -> vbuf[1] ----
    {
#pragma unroll
        for (int s = 0; s < 4; ++s)
            gl2lds16(vsrc + s * 8, vbuf + 8192 + s * 2048 + dst_w);
        __builtin_amdgcn_sched_barrier(0);

        // Phase A: S^T(31) from kbuf[1]
        const f16* kb = kbuf + 8192 + k_lane;
        f32x16 sa, sb;
#pragma unroll
        for (int r = 0; r < 16; ++r) { sa[r] = 0.f; sb[r] = 0.f; }
        __builtin_amdgcn_s_setprio(1);
#pragma unroll
        for (int ck = 0; ck < 16; ++ck) {
            f16x8 kf = *(const f16x8*)(kb + ck * 512);
            if (ck & 1) sb = __builtin_amdgcn_mfma_f32_32x32x16_f16(kf, qf[ck], sb, 0, 0, 0);
            else        sa = __builtin_amdgcn_mfma_f32_32x32x16_f16(kf, qf[ck], sa, 0, 0, 0);
        }
        __builtin_amdgcn_s_setprio(0);
        f32x16 st;
#pragma unroll
        for (int r = 0; r < 16; ++r) st[r] = sa[r] + sb[r];

        // drain V(30) (4 oldest of 8); V(31) stays
        asm volatile("s_waitcnt vmcnt(4)" ::: "memory");
        __builtin_amdgcn_s_barrier();
        __builtin_amdgcn_sched_barrier(0);

        // Phase B: rescale + PV(30) from vbuf[0] (old pf), then softmax(31)+pack
        if (__any(al_prev < 1.f)) {
#pragma unroll
            for (int ct = 0; ct < 8; ++ct)
#pragma unroll
                for (int r = 0; r < 16; ++r) o_acc[ct][r] *= al_prev;
        }
        {
            const f16* vb = vbuf + v_lane;
            __builtin_amdgcn_s_setprio(1);
#pragma unroll
            for (int ct = 0; ct < 8; ++ct) {
                f16x8 v0 = *(const f16x8*)(vb + ct * 256);
                f16x8 v1 = *(const f16x8*)(vb + 4096 + ct * 256);
                o_acc[ct] = __builtin_amdgcn_mfma_f32_32x32x16_f16(v0, pf0, o_acc[ct], 0, 0, 0);
                o_acc[ct] = __builtin_amdgcn_mfma_f32_32x32x16_f16(v1, pf1, o_acc[ct], 0, 0, 0);
            }
            __builtin_amdgcn_s_setprio(0);
        }
        float mx0 = fmaxf(fmaxf(st[0], st[1]), fmaxf(st[2], st[3]));
        float mx1 = fmaxf(fmaxf(st[4], st[5]), fmaxf(st[6], st[7]));
        float mx2 = fmaxf(fmaxf(st[8], st[9]), fmaxf(st[10], st[11]));
        float mx3 = fmaxf(fmaxf(st[12], st[13]), fmaxf(st[14], st[15]));
        float smax = fmaxf(fmaxf(mx0, mx1), fmaxf(mx2, mx3));
        smax = fmaxf(smax, __shfl_xor(smax, 32, 64));
        float mq = __builtin_ceilf(smax * 0.125f) * 8.f;
        float mn = fmaxf(m_, mq);
        float al = __builtin_amdgcn_exp2f((m_ - mn) * L2E);
        float nl = -mn * L2E;
        float p[16];
#pragma unroll
        for (int r = 0; r < 16; ++r)
            p[r] = __builtin_amdgcn_exp2f(st[r] * L2E + nl);
        float a0 = (p[0] + p[1]) + (p[2] + p[3]);
        float a1 = (p[4] + p[5]) + (p[6] + p[7]);
        float a2 = (p[8] + p[9]) + (p[10] + p[11]);
        float a3 = (p[12] + p[13]) + (p[14] + p[15]);
        float rs = (a0 + a1) + (a2 + a3);
        m_ = mn;
        l_ = l_ * al + rs;
        al_prev = al;
        pf0 = pack_pfrag(p, h);
        pf1 = pack_pfrag(p + 8, h);

        // drain V(31); publish
        asm volatile("s_waitcnt vmcnt(0)" ::: "memory");
        __builtin_amdgcn_s_barrier();
        __builtin_amdgcn_sched_barrier(0);

        // final PV(31) from vbuf[1]
        if (__any(al_prev < 1.f)) {
#pragma unroll
            for (int ct = 0; ct < 8; ++ct)
#pragma unroll
                for (int r = 0; r < 16; ++r) o_acc[ct][r] *= al_prev;
        }
        const f16* vb = vbuf + 8192 + v_lane;
#pragma unroll
        for (int ct = 0; ct < 8; ++ct) {
            f16x8 v0 = *(const f16x8*)(vb + ct * 256);
            f16x8 v1 = *(const f16x8*)(vb + 4096 + ct * 256);
            o_acc[ct] = __builtin_amdgcn_mfma_f32_32x32x16_f16(v0, pf0, o_acc[ct], 0, 0, 0);
            o_acc[ct] = __builtin_amdgcn_mfma_f32_32x32x16_f16(v1, pf1, o_acc[ct], 0, 0, 0);
        }
    }

    // ---- epilogue: complete the deferred cross-half l reduction ----
    l_ += __shfl_xor(l_, 32, 64);

    // ---- write partials ----
    int slot = jq * 4 + n;
    int i_out = i0 + w * 32 + j5;
    if (h == 0) {
        g_ml[(slot * 2 + 0) * HW + i_out] = m_;
        g_ml[(slot * 2 + 1) * HW + i_out] = l_;
    }
    float inv = (l_ > 1e-30f) ? 1.f / l_ : 0.f;
    f16* ob = g_opart + slot * CHW + i_out;
#pragma unroll
    for (int ct = 0; ct < 8; ++ct) {
        int cbase = ct * 32 + 4 * h;
#pragma unroll
        for (int r = 0; r < 16; ++r) {
            int c = cbase + (r & 3) + 8 * (r >> 2);
            ob[c * HW] = (f16)(o_acc[ct][r] * inv);
        }
    }
}

// ---------------- kernel 4: merge 4 j-quarters + residual + store (8-wide) ----------------
__global__ __launch_bounds__(256) void k_combine(
    const void* __restrict__ xv, const void* __restrict__ gv, void* __restrict__ outv)
{
    int mode = probe_mode(xv);
    float gam = fin0(mode ? ((const float*)gv)[0] : bf2f(((const ushort_t*)gv)[0]));
    int n = blockIdx.y;
    int off = blockIdx.x * 2048 + threadIdx.x * 8;   // 8 consecutive i, same c
    int i = off & (HW - 1);

    u16x8 op[4];
    float ms[4][8], ls[4][8];
#pragma unroll
    for (int s = 0; s < 4; ++s) {
        int slot = s * 4 + n;
        op[s] = *(const u16x8*)((const ushort_t*)g_opart + slot * CHW + off);
        float4 mA = *(const float4*)&g_ml[(slot * 2 + 0) * HW + i];
        float4 mB = *(const float4*)&g_ml[(slot * 2 + 0) * HW + i + 4];
        float4 lA = *(const float4*)&g_ml[(slot * 2 + 1) * HW + i];
        float4 lB = *(const float4*)&g_ml[(slot * 2 + 1) * HW + i + 4];
        ms[s][0]=mA.x; ms[s][1]=mA.y; ms[s][2]=mA.z; ms[s][3]=mA.w;
        ms[s][4]=mB.x; ms[s][5]=mB.y; ms[s][6]=mB.z; ms[s][7]=mB.w;
        ls[s][0]=lA.x; ls[s][1]=lA.y; ls[s][2]=lA.z; ls[s][3]=lA.w;
        ls[s][4]=lB.x; ls[s][5]=lB.y; ls[s][6]=lB.z; ls[s][7]=lB.w;
    }

    float o[8];
#pragma unroll
    for (int e = 0; e < 8; ++e) {
        float m = fmaxf(fmaxf(ms[0][e], ms[1][e]), fmaxf(ms[2][e], ms[3][e]));
        float num = 0.f, den = 0.f;
#pragma unroll
        for (int s = 0; s < 4; ++s) {
            float wgt = __builtin_amdgcn_exp2f((ms[s][e] - m) * L2E) * ls[s][e];
            union { ushort_t u; f16 h; } cv; cv.u = (ushort_t)op[s][e];
            num += wgt * (float)cv.h;
            den += wgt;
        }
        o[e] = (den > 1e-30f) ? num / den : 0.f;
    }

    if (mode == 0) {
        u16x8 xp = *(const u16x8*)((const ushort_t*)xv + n * CHW + off);
        u16x8 res;
#pragma unroll
        for (int e = 0; e < 8; ++e)
            res[e] = f2bf(fin0(bf2f((ushort_t)xp[e]) + gam * o[e]));
        *(u16x8*)((ushort_t*)outv + n * CHW + off) = res;
    } else {
        const float* xb = (const float*)xv + n * CHW + off;
        float* outb = (float*)outv + n * CHW + off;
        float4 xA = *(const float4*)xb;
        float4 xB = *(const float4*)(xb + 4);
        float4 rA, rB;
        rA.x = fin0(xA.x + gam * o[0]); rA.y = fin0(xA.y + gam * o[1]);
        rA.z = fin0(xA.z + gam * o[2]); rA.w = fin0(xA.w + gam * o[3]);
        rB.x = fin0(xB.x + gam * o[4]); rB.y = fin0(xB.y + gam * o[5]);
        rB.z = fin0(xB.z + gam * o[6]); rB.w = fin0(xB.w + gam * o[7]);
        *(float4*)outb = rA;
        *(float4*)(outb + 4) = rB;
    }
}

extern "C" void kernel_launch(void* const* d_in, const int* in_sizes, int n_in,
                              void* d_out, int out_size, void* d_ws, size_t ws_size,
                              hipStream_t stream) {
    (void)d_ws; (void)ws_size;
    bool ok = (n_in == 8) &&
              in_sizes[0] == 4 * CHW &&
              in_sizes[1] == C_DIM * C_DIM && in_sizes[2] == C_DIM &&
              in_sizes[3] == C_DIM * C_DIM && in_sizes[4] == C_DIM &&
              in_sizes[5] == C_DIM * C_DIM && in_sizes[6] == C_DIM &&
              in_sizes[7] == 1 && out_size == 4 * CHW;
    if (!ok) {
        hipLaunchKernelGGL(k_sentinel, dim3((out_size + 255) / 256), dim3(256), 0, stream,
                           (ushort_t*)d_out, out_size);
        return;
    }
    hipLaunchKernelGGL(k_prep, dim3(64, 4, 5), dim3(256), 0, stream,
                       d_in[0], d_in[1], d_in[2], d_in[3], d_in[4], d_in[5], d_in[6]);
    hipLaunchKernelGGL(k_proj, dim3(32, 6, 4), dim3(256), 0, stream);
    hipLaunchKernelGGL(k_attn, dim3(512), dim3(256), 0, stream);
    hipLaunchKernelGGL(k_combine, dim3(CHW / 2048, 4), dim3(256), 0, stream,
                       d_in[0], d_in[7], d_out);
}